// Round 5
// baseline (1515.869 us; speedup 1.0000x reference)
//
#include <hip/hip_runtime.h>
#include <math.h>

#define NN 3000      // nodes
#define NE 9000      // edges
#define NG 64        // graphs
#define D 300        // EMB
#define NT 6         // towers
#define FO 50        // F_OUT
#define EPSV 1e-5f
#define NB1 3900     // GEMM1 output cols: 3600 (Hd,Hs) + 300 (Xp)

// ---------------- CSR build ----------------
__global__ void k_hist(const int* __restrict__ dst, int* __restrict__ cnt) {
    int e = blockIdx.x * blockDim.x + threadIdx.x;
    if (e < NE) atomicAdd(&cnt[dst[e]], 1);
}

__global__ __launch_bounds__(1024) void k_scan(
    const int* __restrict__ cnt, int* __restrict__ row_ptr, int* __restrict__ tmp_ptr,
    float* __restrict__ degf, float* __restrict__ ampv, float* __restrict__ attv) {
    __shared__ int s_part[1024];
    __shared__ float s_log[1024];
    int tid = threadIdx.x;
    int base = tid * 3;
    int c0 = 0, c1 = 0, c2 = 0; float lg = 0.f;
    if (base + 0 < NN) { c0 = cnt[base + 0]; lg += logf((float)c0 + 1.f); }
    if (base + 1 < NN) { c1 = cnt[base + 1]; lg += logf((float)c1 + 1.f); }
    if (base + 2 < NN) { c2 = cnt[base + 2]; lg += logf((float)c2 + 1.f); }
    s_part[tid] = c0 + c1 + c2;
    s_log[tid] = lg;
    __syncthreads();
    for (int off = 1; off < 1024; off <<= 1) {
        int v = (tid >= off) ? s_part[tid - off] : 0;
        __syncthreads();
        s_part[tid] += v;
        __syncthreads();
    }
    for (int off = 512; off > 0; off >>= 1) {
        if (tid < off) s_log[tid] += s_log[tid + off];
        __syncthreads();
    }
    float avg = s_log[0] / (float)NN;
    int run = (tid > 0) ? s_part[tid - 1] : 0;
    int cs[3] = {c0, c1, c2};
    for (int i = 0; i < 3; i++) {
        int n = base + i;
        if (n < NN) {
            row_ptr[n] = run; tmp_ptr[n] = run;
            int cc = cs[i];
            float dd = (float)(cc > 0 ? cc : 1);
            degf[n] = dd;
            float ld = logf(dd + 1.f);
            ampv[n] = ld / avg;
            attv[n] = avg / ld;
            run += cc;
        }
    }
    if (tid == 1023) row_ptr[NN] = s_part[1023];
}

__global__ void k_fill(const int* __restrict__ src, const int* __restrict__ dst,
                       const int* __restrict__ attr, int* __restrict__ tmp_ptr,
                       int2* __restrict__ edge_dat) {
    int e = blockIdx.x * blockDim.x + threadIdx.x;
    if (e < NE) {
        int d = dst[e];
        int p = atomicAdd(&tmp_ptr[d], 1);
        edge_dat[p] = make_int2(src[e], attr[e]);
    }
}

// ---------------- embedding ----------------
__global__ void k_embed(const int* __restrict__ x, const float* __restrict__ node_emb,
                        float* __restrict__ h, float* __restrict__ rep) {
    int i = blockIdx.x * blockDim.x + threadIdx.x;
    if (i < NN * D) {
        int n = i / D, d = i - n * D;
        float v = node_emb[x[n] * D + d];
        h[i] = v; rep[i] = v;
    }
}

// ---------------- weight packs ----------------
// Bpack1[f][j], j<3600: [s*1800 + t*300 + d] = W_pre[l,t,s*300+f,d]
//               j>=3600: [3600 + t*50 + o] = W_post[l,t,f,o]   (Xp fold)
__global__ void k_pack1(const float* __restrict__ W_pre, const float* __restrict__ W_post,
                        int l, float* __restrict__ Bp) {
    int idx = blockIdx.x * blockDim.x + threadIdx.x;
    if (idx >= 300 * NB1) return;
    int f = idx / NB1, j = idx - f * NB1;
    float v;
    if (j < 3600) {
        int s = j / 1800, r = j - s * 1800;
        int t = r / 300, d = r - t * 300;
        v = W_pre[(((size_t)(l * NT + t) * 900) + s * 300 + f) * 300 + d];
    } else {
        int jj = j - 3600;
        int t = jj / FO, o = jj - t * FO;
        v = W_post[((size_t)(l * NT + t) * 3900 + f) * FO + o];
    }
    Bp[idx] = v;
}

// Bpost[t][f][c], c<160: c<150 -> W_post[l,t,300 + (c/50)*1200 + f, c%50]; else 0
__global__ void k_packpost(const float* __restrict__ W_post, int l, float* __restrict__ Bp) {
    int idx = blockIdx.x * blockDim.x + threadIdx.x;
    if (idx >= NT * 1200 * 160) return;
    int t = idx / 192000, r = idx - t * 192000;
    int f = r / 160, c = r - f * 160;
    float v = 0.f;
    if (c < 150) {
        int k = c / FO, o = c - k * FO;
        v = W_post[((size_t)(l * NT + t) * 3900 + 300 + k * 1200 + f) * FO + o];
    }
    Bp[idx] = v;
}

// ep4[a][f] = sum_k edge_emb[a,k] * W_edge[l,k,f] + b_edge[l,f]   (4 x 300)
__global__ void k_ep4(const float* __restrict__ edge_emb, const float* __restrict__ W_edge,
                      const float* __restrict__ b_edge, int l, float* __restrict__ ep4) {
    int idx = blockIdx.x * blockDim.x + threadIdx.x;
    if (idx >= 4 * 300) return;
    int a = idx / 300, f = idx - a * 300;
    float s = b_edge[l * 300 + f];
    for (int k = 0; k < 300; k++)
        s = fmaf(edge_emb[a * 300 + k], W_edge[((size_t)l * 300 + k) * 300 + f], s);
    ep4[idx] = s;
}

// Ep[a][t*300+d] = sum_f ep4[a,f] * W_pre[l,t,600+f,d] + b_pre[l,t,d]   (4 x 1800)
__global__ void k_ep_proj(const float* __restrict__ ep4, const float* __restrict__ W_pre,
                          const float* __restrict__ b_pre, int l, float* __restrict__ Ep) {
    int idx = blockIdx.x * blockDim.x + threadIdx.x;
    if (idx >= 4 * 1800) return;
    int a = idx / 1800, c = idx - a * 1800;
    int t = c / 300, d = c - t * 300;
    float s = b_pre[(l * NT + t) * 300 + d];
    for (int f = 0; f < 300; f++)
        s = fmaf(ep4[a * 300 + f], W_pre[(((size_t)(l * NT + t) * 900) + 600 + f) * 300 + d], s);
    Ep[idx] = s;
}

// Wlin_f[f][j] = W_lin[l,f,j]*s_j ; b_f[j] = (b_lin-mean)*s + beta
__global__ void k_pack_lin(const float* __restrict__ W_lin, const float* __restrict__ b_lin,
                           const float* __restrict__ gam, const float* __restrict__ bet,
                           const float* __restrict__ mu, const float* __restrict__ var,
                           int l, float* __restrict__ Wf, float* __restrict__ bf) {
    int idx = blockIdx.x * blockDim.x + threadIdx.x;
    if (idx >= 300 * 300) return;
    int f = idx / 300, j = idx - f * 300;
    float s = gam[l * 300 + j] * rsqrtf(var[l * 300 + j] + EPSV);
    Wf[idx] = W_lin[((size_t)l * 300 + f) * 300 + j] * s;
    if (f == 0) bf[j] = (b_lin[l * 300 + j] - mu[l * 300 + j]) * s + bet[l * 300 + j];
}

// ---------------- generic tiled f32 GEMM ----------------
// EPI 0: plain; EPI 1: +bias, relu, rep += v; EPI 2: +bias, BN, relu (head)
template <int EPI>
__global__ __launch_bounds__(256) void k_gemm(
    const float* __restrict__ A, int lda,
    const float* __restrict__ B, int ldb,
    float* __restrict__ C, int ldc,
    int M, int N, int K,
    const float* __restrict__ bias, float* __restrict__ rep,
    const float* __restrict__ gam, const float* __restrict__ bet,
    const float* __restrict__ mu, const float* __restrict__ var) {
    constexpr int BM = 64, BN = 64, BK = 16, LAS = BM + 4;
    __shared__ float As[BK * LAS];
    __shared__ float Bs[BK * BN];
    int tid = threadIdx.x;
    int tx = tid & 15, ty = tid >> 4;
    int bm = blockIdx.y * BM, bn = blockIdx.x * BN;
    int arow = tid >> 2;
    int akq = (tid & 3) * 4;
    int bj = tid & 63, bk0 = tid >> 6;
    float acc[4][4] = {};
    for (int k0 = 0; k0 < K; k0 += BK) {
        {
            float4 av = make_float4(0.f, 0.f, 0.f, 0.f);
            int grow = bm + arow;
            if (grow < M) {
                int gk = k0 + akq;
                if (gk + 3 < K) {
                    av = *(const float4*)&A[(size_t)grow * lda + gk];
                } else {
                    float t0 = (gk + 0 < K) ? A[(size_t)grow * lda + gk + 0] : 0.f;
                    float t1 = (gk + 1 < K) ? A[(size_t)grow * lda + gk + 1] : 0.f;
                    float t2 = (gk + 2 < K) ? A[(size_t)grow * lda + gk + 2] : 0.f;
                    float t3 = (gk + 3 < K) ? A[(size_t)grow * lda + gk + 3] : 0.f;
                    av = make_float4(t0, t1, t2, t3);
                }
            }
            As[(akq + 0) * LAS + arow] = av.x;
            As[(akq + 1) * LAS + arow] = av.y;
            As[(akq + 2) * LAS + arow] = av.z;
            As[(akq + 3) * LAS + arow] = av.w;
        }
        #pragma unroll
        for (int it = 0; it < 4; ++it) {
            int k = bk0 + it * 4;
            int gk = k0 + k, gj = bn + bj;
            float v = 0.f;
            if (gk < K && gj < N) v = B[(size_t)gk * ldb + gj];
            Bs[k * BN + bj] = v;
        }
        __syncthreads();
        #pragma unroll
        for (int kk = 0; kk < BK; ++kk) {
            float4 a = *(const float4*)&As[kk * LAS + ty * 4];
            float4 b = *(const float4*)&Bs[kk * BN + tx * 4];
            float ar[4] = {a.x, a.y, a.z, a.w};
            float br[4] = {b.x, b.y, b.z, b.w};
            #pragma unroll
            for (int i = 0; i < 4; i++)
                #pragma unroll
                for (int j = 0; j < 4; j++)
                    acc[i][j] = fmaf(ar[i], br[j], acc[i][j]);
        }
        __syncthreads();
    }
    #pragma unroll
    for (int i = 0; i < 4; i++) {
        int r = bm + ty * 4 + i;
        if (r >= M) continue;
        #pragma unroll
        for (int j = 0; j < 4; j++) {
            int c = bn + tx * 4 + j;
            if (c >= N) continue;
            float v = acc[i][j];
            if (EPI == 1) {
                v += bias[c];
                v = fmaxf(v, 0.f);
                C[(size_t)r * ldc + c] = v;
                rep[(size_t)r * ldc + c] += v;
            } else if (EPI == 2) {
                v += bias[c];
                v = (v - mu[c]) * rsqrtf(var[c] + EPSV) * gam[c] + bet[c];
                v = fmaxf(v, 0.f);
                C[(size_t)r * ldc + c] = v;
            } else {
                C[(size_t)r * ldc + c] = v;
            }
        }
    }
}

// ---------------- big GEMM1: C[3000xNB1] = A[3000x300] @ B[300xNB1] ------
// 64x128 tile, 4x8 per thread, double-buffered LDS (reg-staged).
__global__ __launch_bounds__(256) void k_gemm1(const float* __restrict__ A,
                                               const float* __restrict__ B,
                                               float* __restrict__ C) {
    constexpr int BM = 64, BN = 128, BK = 16, LAS = BM + 4;
    constexpr int M = 3000, N = NB1, K = 300;
    constexpr int NSTEP = (K + BK - 1) / BK;  // 19 (last step ragged, zero-filled)
    __shared__ float As[2][BK * LAS];
    __shared__ float Bs[2][BK * BN];
    int tid = threadIdx.x;
    int tx = tid & 15, ty = tid >> 4;
    int bm = blockIdx.y * BM, bn = blockIdx.x * BN;
    int arow = tid >> 2, akq = (tid & 3) * 4;
    int grow = bm + arow;
    bool am = grow < M;
    int kB = tid >> 5, cB = (tid & 31) * 4;   // B: rows kB, kB+8; col cB
    int gj = bn + cB;
    bool bj = gj < N;
    float4 rA, rB0, rB1;
    float acc[4][8] = {};

    auto ldA = [&](int k0) {
        int gk = k0 + akq;
        rA = (am && gk < K) ? *(const float4*)&A[(size_t)grow * 300 + gk]
                            : make_float4(0.f, 0.f, 0.f, 0.f);
    };
    auto ldB = [&](int k0) {
        int g0 = k0 + kB, g1 = k0 + kB + 8;
        rB0 = (g0 < K && bj) ? *(const float4*)&B[(size_t)g0 * N + gj]
                             : make_float4(0.f, 0.f, 0.f, 0.f);
        rB1 = (g1 < K && bj) ? *(const float4*)&B[(size_t)g1 * N + gj]
                             : make_float4(0.f, 0.f, 0.f, 0.f);
    };
    auto stW = [&](int b) {
        As[b][(akq + 0) * LAS + arow] = rA.x;
        As[b][(akq + 1) * LAS + arow] = rA.y;
        As[b][(akq + 2) * LAS + arow] = rA.z;
        As[b][(akq + 3) * LAS + arow] = rA.w;
        *(float4*)&Bs[b][kB * BN + cB] = rB0;
        *(float4*)&Bs[b][(kB + 8) * BN + cB] = rB1;
    };

    ldA(0); ldB(0); stW(0);
    __syncthreads();
    int buf = 0;
    for (int step = 0; step < NSTEP; ++step) {
        if (step + 1 < NSTEP) { ldA((step + 1) * BK); ldB((step + 1) * BK); }
        #pragma unroll
        for (int kk = 0; kk < BK; ++kk) {
            float a[4], b[8];
            *(float4*)&a[0] = *(const float4*)&As[buf][kk * LAS + ty * 4];
            *(float4*)&b[0] = *(const float4*)&Bs[buf][kk * BN + tx * 8];
            *(float4*)&b[4] = *(const float4*)&Bs[buf][kk * BN + tx * 8 + 4];
            #pragma unroll
            for (int i = 0; i < 4; i++)
                #pragma unroll
                for (int j = 0; j < 8; j++)
                    acc[i][j] = fmaf(a[i], b[j], acc[i][j]);
        }
        if (step + 1 < NSTEP) {
            int nbuf = buf ^ 1;
            stW(nbuf);
            __syncthreads();
            buf = nbuf;
        }
    }
    int r0 = bm + ty * 4, c0 = bn + tx * 8;
    #pragma unroll
    for (int i = 0; i < 4; i++) {
        int r = r0 + i;
        if (r >= M) break;
        if (c0 + 8 <= N) {
            float4 v0 = make_float4(acc[i][0], acc[i][1], acc[i][2], acc[i][3]);
            float4 v1 = make_float4(acc[i][4], acc[i][5], acc[i][6], acc[i][7]);
            *(float4*)&C[(size_t)r * N + c0] = v0;
            *(float4*)&C[(size_t)r * N + c0 + 4] = v1;
        } else {
            #pragma unroll
            for (int j = 0; j < 8; j++)
                if (c0 + j < N) C[(size_t)r * N + c0 + j] = acc[i][j];
        }
    }
}

// ---------------- post GEMM: split-K=5 per tower, towers in z ----------------
// z in [0,30): t=z%6, kc=z/6. C[z][3000][160] = agg[:, t*1200+kc*240 .. +240] @ Bp[t][kc*240..][160]
// 64x160 tile, 4x10 per thread, double-buffered LDS (reg-staged).
__global__ __launch_bounds__(256) void k_gemmp(const float* __restrict__ agg,
                                               const float* __restrict__ Bp,
                                               float* __restrict__ P) {
    constexpr int BM = 64, BN = 160, BK = 16, LAS = BM + 4, KC = 240;
    constexpr int NSTEP = KC / BK;  // 15
    __shared__ float As[2][BK * LAS];
    __shared__ float Bs[2][BK * BN];
    int z = blockIdx.z;
    int t = z % 6, kc = z / 6;
    const float* A = agg + t * 1200 + kc * KC;        // row stride 7200
    const float* B = Bp + t * 192000 + kc * KC * 160; // row stride 160
    float* C = P + (size_t)z * 480000;
    int tid = threadIdx.x;
    int tx = tid & 15, ty = tid >> 4;
    int bm = blockIdx.y * BM;
    int arow = tid >> 2, akq = (tid & 3) * 4;
    int grow = bm + arow;
    bool am = grow < 3000;
    const float* Arow = A + (size_t)grow * 7200 + akq;
    // Bs: 16x160 = 640 float4; threads cover idx = tid, tid+256, tid+512(<640)
    int kB0 = tid / 40;        int cB0 = (tid - kB0 * 40) * 4;
    int i1 = tid + 256; int kB1 = i1 / 40; int cB1 = (i1 - kB1 * 40) * 4;
    int i2 = tid + 512; int kB2 = i2 / 40; int cB2 = (i2 - kB2 * 40) * 4;
    bool b2 = i2 < 640;
    float4 rA, rB0, rB1, rB2;
    float acc[4][10] = {};

    auto ld = [&](int k0) {
        rA = am ? *(const float4*)&Arow[k0] : make_float4(0.f, 0.f, 0.f, 0.f);
        rB0 = *(const float4*)&B[(size_t)(k0 + kB0) * 160 + cB0];
        rB1 = *(const float4*)&B[(size_t)(k0 + kB1) * 160 + cB1];
        if (b2) rB2 = *(const float4*)&B[(size_t)(k0 + kB2) * 160 + cB2];
    };
    auto stW = [&](int b) {
        As[b][(akq + 0) * LAS + arow] = rA.x;
        As[b][(akq + 1) * LAS + arow] = rA.y;
        As[b][(akq + 2) * LAS + arow] = rA.z;
        As[b][(akq + 3) * LAS + arow] = rA.w;
        *(float4*)&Bs[b][kB0 * BN + cB0] = rB0;
        *(float4*)&Bs[b][kB1 * BN + cB1] = rB1;
        if (b2) *(float4*)&Bs[b][kB2 * BN + cB2] = rB2;
    };

    ld(0); stW(0);
    __syncthreads();
    int buf = 0;
    for (int step = 0; step < NSTEP; ++step) {
        if (step + 1 < NSTEP) ld((step + 1) * BK);
        #pragma unroll
        for (int kk = 0; kk < BK; ++kk) {
            float a[4], b[10];
            *(float4*)&a[0] = *(const float4*)&As[buf][kk * LAS + ty * 4];
            *(float2*)&b[0] = *(const float2*)&Bs[buf][kk * BN + tx * 10 + 0];
            *(float2*)&b[2] = *(const float2*)&Bs[buf][kk * BN + tx * 10 + 2];
            *(float2*)&b[4] = *(const float2*)&Bs[buf][kk * BN + tx * 10 + 4];
            *(float2*)&b[6] = *(const float2*)&Bs[buf][kk * BN + tx * 10 + 6];
            *(float2*)&b[8] = *(const float2*)&Bs[buf][kk * BN + tx * 10 + 8];
            #pragma unroll
            for (int i = 0; i < 4; i++)
                #pragma unroll
                for (int j = 0; j < 10; j++)
                    acc[i][j] = fmaf(a[i], b[j], acc[i][j]);
        }
        if (step + 1 < NSTEP) {
            int nbuf = buf ^ 1;
            stW(nbuf);
            __syncthreads();
            buf = nbuf;
        }
    }
    int r0 = bm + ty * 4, c0 = tx * 10;
    #pragma unroll
    for (int i = 0; i < 4; i++) {
        int r = r0 + i;
        if (r >= 3000) break;
        #pragma unroll
        for (int j = 0; j < 10; j++)
            C[(size_t)r * 160 + c0 + j] = acc[i][j];
    }
}

// ---------------- aggregation (float4) ----------------
__global__ __launch_bounds__(256) void k_agg(
    const float* __restrict__ HH, const float* __restrict__ Ep,
    const int* __restrict__ row_ptr, const int2* __restrict__ edge_dat,
    const float* __restrict__ degf, const int* __restrict__ xv, int use_vocab,
    float* __restrict__ agg) {
    int n = blockIdx.x;
    int e0 = row_ptr[n], e1 = row_ptr[n + 1];
    int cnt = e1 - e0;
    float cntf = (float)cnt;
    float deg = degf[n];
    float inv_deg = 1.f / deg;
    int nrow = use_vocab ? xv[n] : n;
    const float* hdrow = HH + (size_t)nrow * NB1;
    for (int c4 = threadIdx.x; c4 < 450; c4 += 256) {
        int c = c4 * 4;
        float sx = 0.f, sy = 0.f, sz = 0.f, sw = 0.f;
        float qx = 0.f, qy = 0.f, qz = 0.f, qw = 0.f;
        float mnx = INFINITY, mny = INFINITY, mnz = INFINITY, mnw = INFINITY;
        float mxx = -INFINITY, mxy = -INFINITY, mxz = -INFINITY, mxw = -INFINITY;
        for (int e = e0; e < e1; ++e) {
            int2 sa = edge_dat[e];
            int srow = use_vocab ? xv[sa.x] : sa.x;
            float4 hv = *(const float4*)&HH[(size_t)srow * NB1 + 1800 + c];
            float4 ev = *(const float4*)&Ep[(size_t)sa.y * 1800 + c];
            float vx = hv.x + ev.x, vy = hv.y + ev.y, vz = hv.z + ev.z, vw = hv.w + ev.w;
            sx += vx; sy += vy; sz += vz; sw += vw;
            qx = fmaf(vx, vx, qx); qy = fmaf(vy, vy, qy);
            qz = fmaf(vz, vz, qz); qw = fmaf(vw, vw, qw);
            mnx = fminf(mnx, vx); mny = fminf(mny, vy);
            mnz = fminf(mnz, vz); mnw = fminf(mnw, vw);
            mxx = fmaxf(mxx, vx); mxy = fmaxf(mxy, vy);
            mxz = fmaxf(mxz, vz); mxw = fmaxf(mxw, vw);
        }
        float4 hd = *(const float4*)&hdrow[c];
        float4 mean, mnv, mxv, stdv;
        {
            mean.x = (cntf * hd.x + sx) * inv_deg;
            mean.y = (cntf * hd.y + sy) * inv_deg;
            mean.z = (cntf * hd.z + sz) * inv_deg;
            mean.w = (cntf * hd.w + sw) * inv_deg;
            if (cnt > 0) {
                mnv.x = hd.x + mnx; mnv.y = hd.y + mny; mnv.z = hd.z + mnz; mnv.w = hd.w + mnw;
                mxv.x = hd.x + mxx; mxv.y = hd.y + mxy; mxv.z = hd.z + mxz; mxv.w = hd.w + mxw;
            } else {
                mnv = make_float4(0.f, 0.f, 0.f, 0.f);
                mxv = make_float4(0.f, 0.f, 0.f, 0.f);
            }
            float vrx = (cntf * hd.x * hd.x + 2.f * hd.x * sx + qx) * inv_deg - mean.x * mean.x;
            float vry = (cntf * hd.y * hd.y + 2.f * hd.y * sy + qy) * inv_deg - mean.y * mean.y;
            float vrz = (cntf * hd.z * hd.z + 2.f * hd.z * sz + qz) * inv_deg - mean.z * mean.z;
            float vrw = (cntf * hd.w * hd.w + 2.f * hd.w * sw + qw) * inv_deg - mean.w * mean.w;
            stdv.x = sqrtf(fmaxf(vrx, 0.f) + EPSV);
            stdv.y = sqrtf(fmaxf(vry, 0.f) + EPSV);
            stdv.z = sqrtf(fmaxf(vrz, 0.f) + EPSV);
            stdv.w = sqrtf(fmaxf(vrw, 0.f) + EPSV);
        }
        int t = c / 300, d = c - t * 300;
        float* arow = agg + (size_t)n * 7200 + (size_t)t * 1200 + d;
        *(float4*)&arow[0]   = mean;
        *(float4*)&arow[300] = mnv;
        *(float4*)&arow[600] = mxv;
        *(float4*)&arow[900] = stdv;
    }
}

// out_pre[n][t*50+o] = Xp(from HsHd col 3600+) + sum_kc(P1 + amp*P2 + att*P3) + b_post
__global__ void k_combine(const float* __restrict__ HH, const float* __restrict__ P,
                          const float* __restrict__ ampv, const float* __restrict__ attv,
                          const float* __restrict__ b_post_l, const int* __restrict__ xv,
                          int use_vocab, float* __restrict__ out_pre) {
    int i = blockIdx.x * blockDim.x + threadIdx.x;
    if (i >= NN * D) return;
    int n = i / D, j = i - n * D;
    int t = j / FO, o = j - t * FO;
    int nrow = use_vocab ? xv[n] : n;
    float p1 = 0.f, p2 = 0.f, p3 = 0.f;
    #pragma unroll
    for (int kc = 0; kc < 5; kc++) {
        const float* Pr = P + ((size_t)(kc * 6 + t) * 3000 + n) * 160;
        p1 += Pr[o];
        p2 += Pr[50 + o];
        p3 += Pr[100 + o];
    }
    float v = HH[(size_t)nrow * NB1 + 3600 + j] + p1 + ampv[n] * p2 + attv[n] * p3
              + b_post_l[t * FO + o];
    out_pre[i] = v;
}

// ---------------- pooling + head ----------------
__global__ __launch_bounds__(256) void k_pool(const float* __restrict__ rep,
                                              const int* __restrict__ batch,
                                              float* __restrict__ g) {
    __shared__ int s_lo, s_hi;
    int b = blockIdx.x;
    if (threadIdx.x == 0) {
        int lo = 0, hi = NN;
        while (lo < hi) { int m = (lo + hi) >> 1; if (batch[m] < b) lo = m + 1; else hi = m; }
        s_lo = lo;
        int lo2 = lo, hi2 = NN;
        while (lo2 < hi2) { int m = (lo2 + hi2) >> 1; if (batch[m] < b + 1) lo2 = m + 1; else hi2 = m; }
        s_hi = lo2;
    }
    __syncthreads();
    int lo = s_lo, hi = s_hi;
    for (int j = threadIdx.x; j < D; j += blockDim.x) {
        float s = 0.f;
        for (int n = lo; n < hi; ++n) s += rep[(size_t)n * D + j];
        g[b * D + j] = s;
    }
}

__global__ void k_head2(const float* __restrict__ g2, const float* __restrict__ w2,
                        const float* __restrict__ b2, float* __restrict__ out) {
    int b = blockIdx.x;
    int tid = threadIdx.x;  // 64 threads
    float s = 0.f;
    for (int k = tid; k < 300; k += 64) s += g2[b * 300 + k] * w2[k];
    for (int off = 32; off; off >>= 1) s += __shfl_down(s, off, 64);
    if (tid == 0) out[b] = s + b2[0];
}

// ---------------- launch ----------------
extern "C" void kernel_launch(void* const* d_in, const int* in_sizes, int n_in,
                              void* d_out, int out_size, void* d_ws, size_t ws_size,
                              hipStream_t stream) {
    const int* x      = (const int*)d_in[0];
    const int* ei     = (const int*)d_in[1];
    const int* src    = ei;
    const int* dst    = ei + NE;
    const int* eattr  = (const int*)d_in[2];
    const int* batch  = (const int*)d_in[3];
    const float* node_emb = (const float*)d_in[5];
    const float* edge_emb = (const float*)d_in[6];
    const float* W_edge   = (const float*)d_in[7];
    const float* b_edge   = (const float*)d_in[8];
    const float* W_pre    = (const float*)d_in[9];
    const float* b_pre    = (const float*)d_in[10];
    const float* W_post   = (const float*)d_in[11];
    const float* b_post   = (const float*)d_in[12];
    const float* W_lin    = (const float*)d_in[13];
    const float* b_lin    = (const float*)d_in[14];
    const float* bn_gamma = (const float*)d_in[15];
    const float* bn_beta  = (const float*)d_in[16];
    const float* bn_mean  = (const float*)d_in[17];
    const float* bn_var   = (const float*)d_in[18];
    const float* head_w0  = (const float*)d_in[19];
    const float* head_b0  = (const float*)d_in[20];
    const float* gn0_g    = (const float*)d_in[21];
    const float* gn0_b    = (const float*)d_in[22];
    const float* gn0_m    = (const float*)d_in[23];
    const float* gn0_v    = (const float*)d_in[24];
    const float* head_w1  = (const float*)d_in[25];
    const float* head_b1  = (const float*)d_in[26];
    const float* gn1_g    = (const float*)d_in[27];
    const float* gn1_b    = (const float*)d_in[28];
    const float* gn1_m    = (const float*)d_in[29];
    const float* gn1_v    = (const float*)d_in[30];
    const float* head_w2  = (const float*)d_in[31];
    const float* head_b2  = (const float*)d_in[32];
    float* out = (float*)d_out;

    unsigned char* base = (unsigned char*)d_ws;
    size_t off = 0;
    auto alloc = [&](size_t bytes) -> void* {
        void* p = base + off;
        off += (bytes + 255) & ~(size_t)255;
        return p;
    };
    int*   cnt      = (int*)alloc(NN * 4);
    int*   row_ptr  = (int*)alloc((NN + 1) * 4);
    int*   tmp_ptr  = (int*)alloc(NN * 4);
    int2*  edge_dat = (int2*)alloc(NE * 8);
    float* degf     = (float*)alloc(NN * 4);
    float* ampv     = (float*)alloc(NN * 4);
    float* attv     = (float*)alloc(NN * 4);
    float* h        = (float*)alloc((size_t)NN * D * 4);
    float* rep      = (float*)alloc((size_t)NN * D * 4);
    float* HsHd     = (float*)alloc((size_t)NN * NB1 * 4);
    float* Bpack1   = (float*)alloc((size_t)300 * NB1 * 4);
    float* ep4      = (float*)alloc(4 * 300 * 4);
    float* Ep       = (float*)alloc(4 * 1800 * 4);
    float* agg      = (float*)alloc((size_t)NN * 7200 * 4);
    float* Bpost    = (float*)alloc((size_t)NT * 1200 * 160 * 4);
    float* P        = (float*)alloc((size_t)30 * 3000 * 160 * 4);
    float* out_pre  = (float*)alloc((size_t)NN * D * 4);
    float* Wlin_f   = (float*)alloc((size_t)300 * 300 * 4);
    float* b_f      = (float*)alloc(300 * 4);
    float* gsum     = (float*)alloc(NG * D * 4);
    float* gbuf0    = (float*)alloc(NG * 600 * 4);
    float* gbuf1    = (float*)alloc(NG * 300 * 4);
    (void)ws_size; (void)n_in; (void)in_sizes; (void)out_size;

    hipMemsetAsync(cnt, 0, NN * 4, stream);
    k_hist<<<(NE + 255) / 256, 256, 0, stream>>>(dst, cnt);
    k_scan<<<1, 1024, 0, stream>>>(cnt, row_ptr, tmp_ptr, degf, ampv, attv);
    k_fill<<<(NE + 255) / 256, 256, 0, stream>>>(src, dst, eattr, tmp_ptr, edge_dat);
    k_embed<<<(NN * D + 255) / 256, 256, 0, stream>>>(x, node_emb, h, rep);

    for (int l = 0; l < 3; ++l) {  // layer 3 (l==3) output is unused by the reference
        const float* Ain = (l == 0) ? node_emb : h;
        int M = (l == 0) ? 16 : NN;
        int uv = (l == 0) ? 1 : 0;

        k_pack1<<<(300 * NB1 + 255) / 256, 256, 0, stream>>>(W_pre, W_post, l, Bpack1);
        if (l == 0) {
            k_gemm<0><<<dim3((NB1 + 63) / 64, 1, 1), 256, 0, stream>>>(
                Ain, 300, Bpack1, NB1, HsHd, NB1, M, NB1, 300,
                nullptr, nullptr, nullptr, nullptr, nullptr, nullptr);
        } else {
            k_gemm1<<<dim3((NB1 + 127) / 128, 47, 1), 256, 0, stream>>>(Ain, Bpack1, HsHd);
        }

        k_ep4<<<(1200 + 255) / 256, 256, 0, stream>>>(edge_emb, W_edge, b_edge, l, ep4);
        k_ep_proj<<<(7200 + 255) / 256, 256, 0, stream>>>(ep4, W_pre, b_pre, l, Ep);

        k_agg<<<NN, 256, 0, stream>>>(HsHd, Ep, row_ptr, edge_dat, degf, x, uv, agg);

        k_packpost<<<(NT * 1200 * 160 + 255) / 256, 256, 0, stream>>>(W_post, l, Bpost);
        k_gemmp<<<dim3(1, 47, 30), 256, 0, stream>>>(agg, Bpost, P);

        k_combine<<<(NN * D + 255) / 256, 256, 0, stream>>>(
            HsHd, P, ampv, attv, b_post + l * NT * FO, x, uv, out_pre);

        k_pack_lin<<<(300 * 300 + 255) / 256, 256, 0, stream>>>(
            W_lin, b_lin, bn_gamma, bn_beta, bn_mean, bn_var, l, Wlin_f, b_f);
        k_gemm<1><<<dim3(5, 47, 1), 256, 0, stream>>>(
            out_pre, 300, Wlin_f, 300, h, 300, NN, 300, 300,
            b_f, rep, nullptr, nullptr, nullptr, nullptr);
    }

    k_pool<<<NG, 256, 0, stream>>>(rep, batch, gsum);
    k_gemm<2><<<dim3(10, 1, 1), 256, 0, stream>>>(
        gsum, 300, head_w0, 600, gbuf0, 600, NG, 600, 300,
        head_b0, nullptr, gn0_g, gn0_b, gn0_m, gn0_v);
    k_gemm<2><<<dim3(5, 1, 1), 256, 0, stream>>>(
        gbuf0, 600, head_w1, 300, gbuf1, 300, NG, 300, 600,
        head_b1, nullptr, gn1_g, gn1_b, gn1_m, gn1_v);
    k_head2<<<NG, 64, 0, stream>>>(gbuf1, head_w2, head_b2, out);
}

// Round 8
// 1343.306 us; speedup vs baseline: 1.1285x; 1.1285x over previous
//
#include <hip/hip_runtime.h>
#include <math.h>

#define NN 3000      // nodes
#define NE 9000      // edges
#define NG 64        // graphs
#define D 300        // EMB
#define NT 6         // towers
#define FO 50        // F_OUT
#define EPSV 1e-5f
#define NB1 3900     // GEMM1 output cols: 3600 (Hd,Hs) + 300 (Xp)

// ---------------- CSR build ----------------
__global__ void k_hist(const int* __restrict__ dst, int* __restrict__ cnt) {
    int e = blockIdx.x * blockDim.x + threadIdx.x;
    if (e < NE) atomicAdd(&cnt[dst[e]], 1);
}

__global__ __launch_bounds__(1024) void k_scan(
    const int* __restrict__ cnt, int* __restrict__ row_ptr, int* __restrict__ tmp_ptr,
    float* __restrict__ degf, float* __restrict__ ampv, float* __restrict__ attv) {
    __shared__ int s_part[1024];
    __shared__ float s_log[1024];
    int tid = threadIdx.x;
    int base = tid * 3;
    int c0 = 0, c1 = 0, c2 = 0; float lg = 0.f;
    if (base + 0 < NN) { c0 = cnt[base + 0]; lg += logf((float)c0 + 1.f); }
    if (base + 1 < NN) { c1 = cnt[base + 1]; lg += logf((float)c1 + 1.f); }
    if (base + 2 < NN) { c2 = cnt[base + 2]; lg += logf((float)c2 + 1.f); }
    s_part[tid] = c0 + c1 + c2;
    s_log[tid] = lg;
    __syncthreads();
    for (int off = 1; off < 1024; off <<= 1) {
        int v = (tid >= off) ? s_part[tid - off] : 0;
        __syncthreads();
        s_part[tid] += v;
        __syncthreads();
    }
    for (int off = 512; off > 0; off >>= 1) {
        if (tid < off) s_log[tid] += s_log[tid + off];
        __syncthreads();
    }
    float avg = s_log[0] / (float)NN;
    int run = (tid > 0) ? s_part[tid - 1] : 0;
    int cs[3] = {c0, c1, c2};
    for (int i = 0; i < 3; i++) {
        int n = base + i;
        if (n < NN) {
            row_ptr[n] = run; tmp_ptr[n] = run;
            int cc = cs[i];
            float dd = (float)(cc > 0 ? cc : 1);
            degf[n] = dd;
            float ld = logf(dd + 1.f);
            ampv[n] = ld / avg;
            attv[n] = avg / ld;
            run += cc;
        }
    }
    if (tid == 1023) row_ptr[NN] = s_part[1023];
}

__global__ void k_fill(const int* __restrict__ src, const int* __restrict__ dst,
                       const int* __restrict__ attr, int* __restrict__ tmp_ptr,
                       int2* __restrict__ edge_dat) {
    int e = blockIdx.x * blockDim.x + threadIdx.x;
    if (e < NE) {
        int d = dst[e];
        int p = atomicAdd(&tmp_ptr[d], 1);
        edge_dat[p] = make_int2(src[e], attr[e]);
    }
}

// ---------------- embedding ----------------
__global__ void k_embed(const int* __restrict__ x, const float* __restrict__ node_emb,
                        float* __restrict__ h, float* __restrict__ rep) {
    int i = blockIdx.x * blockDim.x + threadIdx.x;
    if (i < NN * D) {
        int n = i / D, d = i - n * D;
        float v = node_emb[x[n] * D + d];
        h[i] = v; rep[i] = v;
    }
}

// ---------------- weight packs ----------------
// Bpack1[f][j], j<3600: [s*1800 + t*300 + d] = W_pre[l,t,s*300+f,d]
//               j>=3600: [3600 + t*50 + o] = W_post[l,t,f,o]   (Xp fold)
__global__ void k_pack1(const float* __restrict__ W_pre, const float* __restrict__ W_post,
                        int l, float* __restrict__ Bp) {
    int idx = blockIdx.x * blockDim.x + threadIdx.x;
    if (idx >= 300 * NB1) return;
    int f = idx / NB1, j = idx - f * NB1;
    float v;
    if (j < 3600) {
        int s = j / 1800, r = j - s * 1800;
        int t = r / 300, d = r - t * 300;
        v = W_pre[(((size_t)(l * NT + t) * 900) + s * 300 + f) * 300 + d];
    } else {
        int jj = j - 3600;
        int t = jj / FO, o = jj - t * FO;
        v = W_post[((size_t)(l * NT + t) * 3900 + f) * FO + o];
    }
    Bp[idx] = v;
}

// Bpost[t][f][c], c<160: c<150 -> W_post[l,t,300 + (c/50)*1200 + f, c%50]; else 0
__global__ void k_packpost(const float* __restrict__ W_post, int l, float* __restrict__ Bp) {
    int idx = blockIdx.x * blockDim.x + threadIdx.x;
    if (idx >= NT * 1200 * 160) return;
    int t = idx / 192000, r = idx - t * 192000;
    int f = r / 160, c = r - f * 160;
    float v = 0.f;
    if (c < 150) {
        int k = c / FO, o = c - k * FO;
        v = W_post[((size_t)(l * NT + t) * 3900 + 300 + k * 1200 + f) * FO + o];
    }
    Bp[idx] = v;
}

// ep4[a][f] = sum_k edge_emb[a,k] * W_edge[l,k,f] + b_edge[l,f]   (4 x 300)
__global__ void k_ep4(const float* __restrict__ edge_emb, const float* __restrict__ W_edge,
                      const float* __restrict__ b_edge, int l, float* __restrict__ ep4) {
    int idx = blockIdx.x * blockDim.x + threadIdx.x;
    if (idx >= 4 * 300) return;
    int a = idx / 300, f = idx - a * 300;
    float s = b_edge[l * 300 + f];
    for (int k = 0; k < 300; k++)
        s = fmaf(edge_emb[a * 300 + k], W_edge[((size_t)l * 300 + k) * 300 + f], s);
    ep4[idx] = s;
}

// Ep[a][t*300+d] = sum_f ep4[a,f] * W_pre[l,t,600+f,d] + b_pre[l,t,d]   (4 x 1800)
__global__ void k_ep_proj(const float* __restrict__ ep4, const float* __restrict__ W_pre,
                          const float* __restrict__ b_pre, int l, float* __restrict__ Ep) {
    int idx = blockIdx.x * blockDim.x + threadIdx.x;
    if (idx >= 4 * 1800) return;
    int a = idx / 1800, c = idx - a * 1800;
    int t = c / 300, d = c - t * 300;
    float s = b_pre[(l * NT + t) * 300 + d];
    for (int f = 0; f < 300; f++)
        s = fmaf(ep4[a * 300 + f], W_pre[(((size_t)(l * NT + t) * 900) + 600 + f) * 300 + d], s);
    Ep[idx] = s;
}

// Wlin_f[f][j] = W_lin[l,f,j]*s_j ; b_f[j] = (b_lin-mean)*s + beta
__global__ void k_pack_lin(const float* __restrict__ W_lin, const float* __restrict__ b_lin,
                           const float* __restrict__ gam, const float* __restrict__ bet,
                           const float* __restrict__ mu, const float* __restrict__ var,
                           int l, float* __restrict__ Wf, float* __restrict__ bf) {
    int idx = blockIdx.x * blockDim.x + threadIdx.x;
    if (idx >= 300 * 300) return;
    int f = idx / 300, j = idx - f * 300;
    float s = gam[l * 300 + j] * rsqrtf(var[l * 300 + j] + EPSV);
    Wf[idx] = W_lin[((size_t)l * 300 + f) * 300 + j] * s;
    if (f == 0) bf[j] = (b_lin[l * 300 + j] - mu[l * 300 + j]) * s + bet[l * 300 + j];
}

// ---------------- generic tiled f32 GEMM ----------------
// EPI 0: plain; EPI 1: +bias, relu, rep += v; EPI 2: +bias, BN, relu (head)
template <int EPI>
__global__ __launch_bounds__(256) void k_gemm(
    const float* __restrict__ A, int lda,
    const float* __restrict__ B, int ldb,
    float* __restrict__ C, int ldc,
    int M, int N, int K,
    const float* __restrict__ bias, float* __restrict__ rep,
    const float* __restrict__ gam, const float* __restrict__ bet,
    const float* __restrict__ mu, const float* __restrict__ var) {
    constexpr int BM = 64, BN = 64, BK = 16, LAS = BM + 4;
    __shared__ float As[BK * LAS];
    __shared__ float Bs[BK * BN];
    int tid = threadIdx.x;
    int tx = tid & 15, ty = tid >> 4;
    int bm = blockIdx.y * BM, bn = blockIdx.x * BN;
    int arow = tid >> 2;
    int akq = (tid & 3) * 4;
    int bj = tid & 63, bk0 = tid >> 6;
    float acc[4][4] = {};
    for (int k0 = 0; k0 < K; k0 += BK) {
        {
            float4 av = make_float4(0.f, 0.f, 0.f, 0.f);
            int grow = bm + arow;
            if (grow < M) {
                int gk = k0 + akq;
                if (gk + 3 < K) {
                    av = *(const float4*)&A[(size_t)grow * lda + gk];
                } else {
                    float t0 = (gk + 0 < K) ? A[(size_t)grow * lda + gk + 0] : 0.f;
                    float t1 = (gk + 1 < K) ? A[(size_t)grow * lda + gk + 1] : 0.f;
                    float t2 = (gk + 2 < K) ? A[(size_t)grow * lda + gk + 2] : 0.f;
                    float t3 = (gk + 3 < K) ? A[(size_t)grow * lda + gk + 3] : 0.f;
                    av = make_float4(t0, t1, t2, t3);
                }
            }
            As[(akq + 0) * LAS + arow] = av.x;
            As[(akq + 1) * LAS + arow] = av.y;
            As[(akq + 2) * LAS + arow] = av.z;
            As[(akq + 3) * LAS + arow] = av.w;
        }
        #pragma unroll
        for (int it = 0; it < 4; ++it) {
            int k = bk0 + it * 4;
            int gk = k0 + k, gj = bn + bj;
            float v = 0.f;
            if (gk < K && gj < N) v = B[(size_t)gk * ldb + gj];
            Bs[k * BN + bj] = v;
        }
        __syncthreads();
        #pragma unroll
        for (int kk = 0; kk < BK; ++kk) {
            float4 a = *(const float4*)&As[kk * LAS + ty * 4];
            float4 b = *(const float4*)&Bs[kk * BN + tx * 4];
            float ar[4] = {a.x, a.y, a.z, a.w};
            float br[4] = {b.x, b.y, b.z, b.w};
            #pragma unroll
            for (int i = 0; i < 4; i++)
                #pragma unroll
                for (int j = 0; j < 4; j++)
                    acc[i][j] = fmaf(ar[i], br[j], acc[i][j]);
        }
        __syncthreads();
    }
    #pragma unroll
    for (int i = 0; i < 4; i++) {
        int r = bm + ty * 4 + i;
        if (r >= M) continue;
        #pragma unroll
        for (int j = 0; j < 4; j++) {
            int c = bn + tx * 4 + j;
            if (c >= N) continue;
            float v = acc[i][j];
            if (EPI == 1) {
                v += bias[c];
                v = fmaxf(v, 0.f);
                C[(size_t)r * ldc + c] = v;
                rep[(size_t)r * ldc + c] += v;
            } else if (EPI == 2) {
                v += bias[c];
                v = (v - mu[c]) * rsqrtf(var[c] + EPSV) * gam[c] + bet[c];
                v = fmaxf(v, 0.f);
                C[(size_t)r * ldc + c] = v;
            } else {
                C[(size_t)r * ldc + c] = v;
            }
        }
    }
}

// ---------------- big GEMM1: C[3000xNB1] = A[3000x300] @ B[300xNB1] ------
// 128x128 tile, 8x8 per thread (round-4 proven version).
__global__ __launch_bounds__(256) void k_gemm1(const float* __restrict__ A,
                                               const float* __restrict__ B,
                                               float* __restrict__ C) {
    constexpr int BM = 128, BN = 128, BK = 16, LAS = BM + 4;
    constexpr int M = 3000, N = NB1, K = 300;
    __shared__ float As[BK * LAS];
    __shared__ float Bs[BK * BN];
    int tid = threadIdx.x;
    int tx = tid & 15, ty = tid >> 4;
    int bm = blockIdx.y * BM, bn = blockIdx.x * BN;
    float acc[8][8] = {};
    for (int k0 = 0; k0 < K; k0 += BK) {
        #pragma unroll
        for (int it = 0; it < 2; ++it) {
            int i = tid + it * 256;
            int row = i >> 2, kq = (i & 3) * 4;
            int grow = bm + row, gk = k0 + kq;
            float4 av = make_float4(0.f, 0.f, 0.f, 0.f);
            // K=300, gk multiple of 4 -> gk<K implies full float4 in-bounds
            if (grow < M && gk < K) av = *(const float4*)&A[(size_t)grow * 300 + gk];
            As[(kq + 0) * LAS + row] = av.x;
            As[(kq + 1) * LAS + row] = av.y;
            As[(kq + 2) * LAS + row] = av.z;
            As[(kq + 3) * LAS + row] = av.w;
        }
        #pragma unroll
        for (int it = 0; it < 2; ++it) {
            int i = tid + it * 256;
            int k = i >> 5, c = (i & 31) * 4;
            int gk = k0 + k, gj = bn + c;
            float4 bv = make_float4(0.f, 0.f, 0.f, 0.f);
            // N, gj multiples of 4 -> gj<N implies full float4 in-bounds
            if (gk < K && gj < N) bv = *(const float4*)&B[(size_t)gk * N + gj];
            *(float4*)&Bs[k * BN + c] = bv;
        }
        __syncthreads();
        #pragma unroll
        for (int kk = 0; kk < BK; ++kk) {
            float a[8], b[8];
            *(float4*)&a[0] = *(const float4*)&As[kk * LAS + ty * 8];
            *(float4*)&a[4] = *(const float4*)&As[kk * LAS + ty * 8 + 4];
            *(float4*)&b[0] = *(const float4*)&Bs[kk * BN + tx * 8];
            *(float4*)&b[4] = *(const float4*)&Bs[kk * BN + tx * 8 + 4];
            #pragma unroll
            for (int i = 0; i < 8; i++)
                #pragma unroll
                for (int j = 0; j < 8; j++)
                    acc[i][j] = fmaf(a[i], b[j], acc[i][j]);
        }
        __syncthreads();
    }
    int r0 = bm + ty * 8, c0 = bn + tx * 8;
    #pragma unroll
    for (int i = 0; i < 8; i++) {
        int r = r0 + i;
        if (r >= M) break;
        if (c0 + 8 <= N) {
            float4 v0 = make_float4(acc[i][0], acc[i][1], acc[i][2], acc[i][3]);
            float4 v1 = make_float4(acc[i][4], acc[i][5], acc[i][6], acc[i][7]);
            *(float4*)&C[(size_t)r * N + c0] = v0;
            *(float4*)&C[(size_t)r * N + c0 + 4] = v1;
        } else {
            #pragma unroll
            for (int j = 0; j < 8; j++)
                if (c0 + j < N) C[(size_t)r * N + c0 + j] = acc[i][j];
        }
    }
}

// ---------------- post GEMM: split-K=5 per tower, towers in z ----------------
// z in [0,30): t=z%6, kc=z/6. C[z][3000][160] = agg[:, t*1200+kc*240 .. +240] @ Bp[t][kc*240..][160]
// Round-4 single-buffer body (VGPR ~60), occupancy raised via more split-K slices.
__global__ __launch_bounds__(256) void k_gemmp(const float* __restrict__ agg,
                                               const float* __restrict__ Bp,
                                               float* __restrict__ P) {
    constexpr int BM = 64, BN = 160, BK = 16, LAS = BM + 4, KC = 240;
    __shared__ float As[BK * LAS];
    __shared__ float Bs[BK * BN];
    int z = blockIdx.z;
    int t = z % 6, kc = z / 6;
    const float* A = agg + t * 1200 + kc * KC;        // row stride 7200
    const float* B = Bp + t * 192000 + kc * KC * 160; // row stride 160
    float* C = P + (size_t)z * 480000;
    int tid = threadIdx.x;
    int tx = tid & 15, ty = tid >> 4;
    int bm = blockIdx.y * BM;
    float acc[4][10] = {};
    for (int k0 = 0; k0 < KC; k0 += BK) {
        {
            int row = tid >> 2, kq = (tid & 3) * 4;
            int grow = bm + row;
            float4 av = make_float4(0.f, 0.f, 0.f, 0.f);
            if (grow < 3000) av = *(const float4*)&A[(size_t)grow * 7200 + k0 + kq];
            As[(kq + 0) * LAS + row] = av.x;
            As[(kq + 1) * LAS + row] = av.y;
            As[(kq + 2) * LAS + row] = av.z;
            As[(kq + 3) * LAS + row] = av.w;
        }
        #pragma unroll
        for (int it = 0; it < 3; ++it) {
            int i = tid + it * 256;
            if (i < 640) {
                int k = i / 40, c = (i - k * 40) * 4;
                *(float4*)&Bs[k * BN + c] = *(const float4*)&B[(size_t)(k0 + k) * 160 + c];
            }
        }
        __syncthreads();
        #pragma unroll
        for (int kk = 0; kk < BK; ++kk) {
            float a[4], b[10];
            *(float4*)&a[0] = *(const float4*)&As[kk * LAS + ty * 4];
            #pragma unroll
            for (int j = 0; j < 10; j++) b[j] = Bs[kk * BN + tx * 10 + j];
            #pragma unroll
            for (int i = 0; i < 4; i++)
                #pragma unroll
                for (int j = 0; j < 10; j++)
                    acc[i][j] = fmaf(a[i], b[j], acc[i][j]);
        }
        __syncthreads();
    }
    int r0 = bm + ty * 4, c0 = tx * 10;
    #pragma unroll
    for (int i = 0; i < 4; i++) {
        int r = r0 + i;
        if (r >= 3000) break;
        #pragma unroll
        for (int j = 0; j < 10; j++)
            C[(size_t)r * 160 + c0 + j] = acc[i][j];
    }
}

// ---------------- aggregation (float4) ----------------
__global__ __launch_bounds__(256) void k_agg(
    const float* __restrict__ HH, const float* __restrict__ Ep,
    const int* __restrict__ row_ptr, const int2* __restrict__ edge_dat,
    const float* __restrict__ degf, const int* __restrict__ xv, int use_vocab,
    float* __restrict__ agg) {
    int n = blockIdx.x;
    int e0 = row_ptr[n], e1 = row_ptr[n + 1];
    int cnt = e1 - e0;
    float cntf = (float)cnt;
    float deg = degf[n];
    float inv_deg = 1.f / deg;
    int nrow = use_vocab ? xv[n] : n;
    const float* hdrow = HH + (size_t)nrow * NB1;
    for (int c4 = threadIdx.x; c4 < 450; c4 += 256) {
        int c = c4 * 4;
        float sx = 0.f, sy = 0.f, sz = 0.f, sw = 0.f;
        float qx = 0.f, qy = 0.f, qz = 0.f, qw = 0.f;
        float mnx = INFINITY, mny = INFINITY, mnz = INFINITY, mnw = INFINITY;
        float mxx = -INFINITY, mxy = -INFINITY, mxz = -INFINITY, mxw = -INFINITY;
        for (int e = e0; e < e1; ++e) {
            int2 sa = edge_dat[e];
            int srow = use_vocab ? xv[sa.x] : sa.x;
            float4 hv = *(const float4*)&HH[(size_t)srow * NB1 + 1800 + c];
            float4 ev = *(const float4*)&Ep[(size_t)sa.y * 1800 + c];
            float vx = hv.x + ev.x, vy = hv.y + ev.y, vz = hv.z + ev.z, vw = hv.w + ev.w;
            sx += vx; sy += vy; sz += vz; sw += vw;
            qx = fmaf(vx, vx, qx); qy = fmaf(vy, vy, qy);
            qz = fmaf(vz, vz, qz); qw = fmaf(vw, vw, qw);
            mnx = fminf(mnx, vx); mny = fminf(mny, vy);
            mnz = fminf(mnz, vz); mnw = fminf(mnw, vw);
            mxx = fmaxf(mxx, vx); mxy = fmaxf(mxy, vy);
            mxz = fmaxf(mxz, vz); mxw = fmaxf(mxw, vw);
        }
        float4 hd = *(const float4*)&hdrow[c];
        float4 mean, mnv, mxv, stdv;
        {
            mean.x = (cntf * hd.x + sx) * inv_deg;
            mean.y = (cntf * hd.y + sy) * inv_deg;
            mean.z = (cntf * hd.z + sz) * inv_deg;
            mean.w = (cntf * hd.w + sw) * inv_deg;
            if (cnt > 0) {
                mnv.x = hd.x + mnx; mnv.y = hd.y + mny; mnv.z = hd.z + mnz; mnv.w = hd.w + mnw;
                mxv.x = hd.x + mxx; mxv.y = hd.y + mxy; mxv.z = hd.z + mxz; mxv.w = hd.w + mxw;
            } else {
                mnv = make_float4(0.f, 0.f, 0.f, 0.f);
                mxv = make_float4(0.f, 0.f, 0.f, 0.f);
            }
            float vrx = (cntf * hd.x * hd.x + 2.f * hd.x * sx + qx) * inv_deg - mean.x * mean.x;
            float vry = (cntf * hd.y * hd.y + 2.f * hd.y * sy + qy) * inv_deg - mean.y * mean.y;
            float vrz = (cntf * hd.z * hd.z + 2.f * hd.z * sz + qz) * inv_deg - mean.z * mean.z;
            float vrw = (cntf * hd.w * hd.w + 2.f * hd.w * sw + qw) * inv_deg - mean.w * mean.w;
            stdv.x = sqrtf(fmaxf(vrx, 0.f) + EPSV);
            stdv.y = sqrtf(fmaxf(vry, 0.f) + EPSV);
            stdv.z = sqrtf(fmaxf(vrz, 0.f) + EPSV);
            stdv.w = sqrtf(fmaxf(vrw, 0.f) + EPSV);
        }
        int t = c / 300, d = c - t * 300;
        float* arow = agg + (size_t)n * 7200 + (size_t)t * 1200 + d;
        *(float4*)&arow[0]   = mean;
        *(float4*)&arow[300] = mnv;
        *(float4*)&arow[600] = mxv;
        *(float4*)&arow[900] = stdv;
    }
}

// out_pre[n][t*50+o] = Xp(from HsHd col 3600+) + sum_kc(P1 + amp*P2 + att*P3) + b_post
__global__ void k_combine(const float* __restrict__ HH, const float* __restrict__ P,
                          const float* __restrict__ ampv, const float* __restrict__ attv,
                          const float* __restrict__ b_post_l, const int* __restrict__ xv,
                          int use_vocab, float* __restrict__ out_pre) {
    int i = blockIdx.x * blockDim.x + threadIdx.x;
    if (i >= NN * D) return;
    int n = i / D, j = i - n * D;
    int t = j / FO, o = j - t * FO;
    int nrow = use_vocab ? xv[n] : n;
    float p1 = 0.f, p2 = 0.f, p3 = 0.f;
    #pragma unroll
    for (int kc = 0; kc < 5; kc++) {
        const float* Pr = P + ((size_t)(kc * 6 + t) * 3000 + n) * 160;
        p1 += Pr[o];
        p2 += Pr[50 + o];
        p3 += Pr[100 + o];
    }
    float v = HH[(size_t)nrow * NB1 + 3600 + j] + p1 + ampv[n] * p2 + attv[n] * p3
              + b_post_l[t * FO + o];
    out_pre[i] = v;
}

// ---------------- pooling + head ----------------
__global__ __launch_bounds__(256) void k_pool(const float* __restrict__ rep,
                                              const int* __restrict__ batch,
                                              float* __restrict__ g) {
    __shared__ int s_lo, s_hi;
    int b = blockIdx.x;
    if (threadIdx.x == 0) {
        int lo = 0, hi = NN;
        while (lo < hi) { int m = (lo + hi) >> 1; if (batch[m] < b) lo = m + 1; else hi = m; }
        s_lo = lo;
        int lo2 = lo, hi2 = NN;
        while (lo2 < hi2) { int m = (lo2 + hi2) >> 1; if (batch[m] < b + 1) lo2 = m + 1; else hi2 = m; }
        s_hi = lo2;
    }
    __syncthreads();
    int lo = s_lo, hi = s_hi;
    for (int j = threadIdx.x; j < D; j += blockDim.x) {
        float s = 0.f;
        for (int n = lo; n < hi; ++n) s += rep[(size_t)n * D + j];
        g[b * D + j] = s;
    }
}

__global__ void k_head2(const float* __restrict__ g2, const float* __restrict__ w2,
                        const float* __restrict__ b2, float* __restrict__ out) {
    int b = blockIdx.x;
    int tid = threadIdx.x;  // 64 threads
    float s = 0.f;
    for (int k = tid; k < 300; k += 64) s += g2[b * 300 + k] * w2[k];
    for (int off = 32; off; off >>= 1) s += __shfl_down(s, off, 64);
    if (tid == 0) out[b] = s + b2[0];
}

// ---------------- launch ----------------
extern "C" void kernel_launch(void* const* d_in, const int* in_sizes, int n_in,
                              void* d_out, int out_size, void* d_ws, size_t ws_size,
                              hipStream_t stream) {
    const int* x      = (const int*)d_in[0];
    const int* ei     = (const int*)d_in[1];
    const int* src    = ei;
    const int* dst    = ei + NE;
    const int* eattr  = (const int*)d_in[2];
    const int* batch  = (const int*)d_in[3];
    const float* node_emb = (const float*)d_in[5];
    const float* edge_emb = (const float*)d_in[6];
    const float* W_edge   = (const float*)d_in[7];
    const float* b_edge   = (const float*)d_in[8];
    const float* W_pre    = (const float*)d_in[9];
    const float* b_pre    = (const float*)d_in[10];
    const float* W_post   = (const float*)d_in[11];
    const float* b_post   = (const float*)d_in[12];
    const float* W_lin    = (const float*)d_in[13];
    const float* b_lin    = (const float*)d_in[14];
    const float* bn_gamma = (const float*)d_in[15];
    const float* bn_beta  = (const float*)d_in[16];
    const float* bn_mean  = (const float*)d_in[17];
    const float* bn_var   = (const float*)d_in[18];
    const float* head_w0  = (const float*)d_in[19];
    const float* head_b0  = (const float*)d_in[20];
    const float* gn0_g    = (const float*)d_in[21];
    const float* gn0_b    = (const float*)d_in[22];
    const float* gn0_m    = (const float*)d_in[23];
    const float* gn0_v    = (const float*)d_in[24];
    const float* head_w1  = (const float*)d_in[25];
    const float* head_b1  = (const float*)d_in[26];
    const float* gn1_g    = (const float*)d_in[27];
    const float* gn1_b    = (const float*)d_in[28];
    const float* gn1_m    = (const float*)d_in[29];
    const float* gn1_v    = (const float*)d_in[30];
    const float* head_w2  = (const float*)d_in[31];
    const float* head_b2  = (const float*)d_in[32];
    float* out = (float*)d_out;

    unsigned char* base = (unsigned char*)d_ws;
    size_t off = 0;
    auto alloc = [&](size_t bytes) -> void* {
        void* p = base + off;
        off += (bytes + 255) & ~(size_t)255;
        return p;
    };
    int*   cnt      = (int*)alloc(NN * 4);
    int*   row_ptr  = (int*)alloc((NN + 1) * 4);
    int*   tmp_ptr  = (int*)alloc(NN * 4);
    int2*  edge_dat = (int2*)alloc(NE * 8);
    float* degf     = (float*)alloc(NN * 4);
    float* ampv     = (float*)alloc(NN * 4);
    float* attv     = (float*)alloc(NN * 4);
    float* h        = (float*)alloc((size_t)NN * D * 4);
    float* rep      = (float*)alloc((size_t)NN * D * 4);
    float* HsHd     = (float*)alloc((size_t)NN * NB1 * 4);
    float* Bpack1   = (float*)alloc((size_t)300 * NB1 * 4);
    float* ep4      = (float*)alloc(4 * 300 * 4);
    float* Ep       = (float*)alloc(4 * 1800 * 4);
    float* agg      = (float*)alloc((size_t)NN * 7200 * 4);
    float* Bpost    = (float*)alloc((size_t)NT * 1200 * 160 * 4);
    float* P        = (float*)alloc((size_t)30 * 3000 * 160 * 4);
    float* out_pre  = (float*)alloc((size_t)NN * D * 4);
    float* Wlin_f   = (float*)alloc((size_t)300 * 300 * 4);
    float* b_f      = (float*)alloc(300 * 4);
    float* gsum     = (float*)alloc(NG * D * 4);
    float* gbuf0    = (float*)alloc(NG * 600 * 4);
    float* gbuf1    = (float*)alloc(NG * 300 * 4);
    (void)ws_size; (void)n_in; (void)in_sizes; (void)out_size;

    hipMemsetAsync(cnt, 0, NN * 4, stream);
    k_hist<<<(NE + 255) / 256, 256, 0, stream>>>(dst, cnt);
    k_scan<<<1, 1024, 0, stream>>>(cnt, row_ptr, tmp_ptr, degf, ampv, attv);
    k_fill<<<(NE + 255) / 256, 256, 0, stream>>>(src, dst, eattr, tmp_ptr, edge_dat);
    k_embed<<<(NN * D + 255) / 256, 256, 0, stream>>>(x, node_emb, h, rep);

    for (int l = 0; l < 3; ++l) {  // layer 3 (l==3) output is unused by the reference
        const float* Ain = (l == 0) ? node_emb : h;
        int M = (l == 0) ? 16 : NN;
        int uv = (l == 0) ? 1 : 0;

        k_pack1<<<(300 * NB1 + 255) / 256, 256, 0, stream>>>(W_pre, W_post, l, Bpack1);
        if (l == 0) {
            k_gemm<0><<<dim3((NB1 + 63) / 64, 1, 1), 256, 0, stream>>>(
                Ain, 300, Bpack1, NB1, HsHd, NB1, M, NB1, 300,
                nullptr, nullptr, nullptr, nullptr, nullptr, nullptr);
        } else {
            k_gemm1<<<dim3((NB1 + 127) / 128, 24, 1), 256, 0, stream>>>(Ain, Bpack1, HsHd);
        }

        k_ep4<<<(1200 + 255) / 256, 256, 0, stream>>>(edge_emb, W_edge, b_edge, l, ep4);
        k_ep_proj<<<(7200 + 255) / 256, 256, 0, stream>>>(ep4, W_pre, b_pre, l, Ep);

        k_agg<<<NN, 256, 0, stream>>>(HsHd, Ep, row_ptr, edge_dat, degf, x, uv, agg);

        k_packpost<<<(NT * 1200 * 160 + 255) / 256, 256, 0, stream>>>(W_post, l, Bpost);
        k_gemmp<<<dim3(1, 47, 30), 256, 0, stream>>>(agg, Bpost, P);

        k_combine<<<(NN * D + 255) / 256, 256, 0, stream>>>(
            HsHd, P, ampv, attv, b_post + l * NT * FO, x, uv, out_pre);

        k_pack_lin<<<(300 * 300 + 255) / 256, 256, 0, stream>>>(
            W_lin, b_lin, bn_gamma, bn_beta, bn_mean, bn_var, l, Wlin_f, b_f);
        k_gemm<1><<<dim3(5, 47, 1), 256, 0, stream>>>(
            out_pre, 300, Wlin_f, 300, h, 300, NN, 300, 300,
            b_f, rep, nullptr, nullptr, nullptr, nullptr);
    }

    k_pool<<<NG, 256, 0, stream>>>(rep, batch, gsum);
    k_gemm<2><<<dim3(10, 1, 1), 256, 0, stream>>>(
        gsum, 300, head_w0, 600, gbuf0, 600, NG, 600, 300,
        head_b0, nullptr, gn0_g, gn0_b, gn0_m, gn0_v);
    k_gemm<2><<<dim3(5, 1, 1), 256, 0, stream>>>(
        gbuf0, 600, head_w1, 300, gbuf1, 300, NG, 300, 600,
        head_b1, nullptr, gn1_g, gn1_b, gn1_m, gn1_v);
    k_head2<<<NG, 64, 0, stream>>>(gbuf1, head_w2, head_b2, out);
}

// Round 9
// 1285.715 us; speedup vs baseline: 1.1790x; 1.0448x over previous
//
#include <hip/hip_runtime.h>
#include <hip/hip_bf16.h>
#include <math.h>

#define NN 3000      // nodes
#define NE 9000      // edges
#define NG 64        // graphs
#define D 300        // EMB
#define NT 6         // towers
#define FO 50        // F_OUT
#define EPSV 1e-5f
#define NB1 3900     // GEMM1 output cols: 3600 (Hd,Hs) + 300 (Xp)
#define MP 3008      // padded rows for MFMA gemm1
#define NP 3904      // padded cols for MFMA gemm1
#define KP 320       // padded K for MFMA gemm1

typedef __attribute__((ext_vector_type(8))) short short8;
typedef __attribute__((ext_vector_type(4))) float floatx4;

__device__ inline unsigned short f2bf_rne(float f) {
    unsigned u = __float_as_uint(f);
    unsigned r = (u + 0x7FFF + ((u >> 16) & 1)) >> 16;
    return (unsigned short)r;
}
__device__ inline float bf2f(unsigned short h) {
    return __uint_as_float((unsigned)h << 16);
}

// ---------------- CSR build ----------------
__global__ void k_hist(const int* __restrict__ dst, int* __restrict__ cnt) {
    int e = blockIdx.x * blockDim.x + threadIdx.x;
    if (e < NE) atomicAdd(&cnt[dst[e]], 1);
}

__global__ __launch_bounds__(1024) void k_scan(
    const int* __restrict__ cnt, int* __restrict__ row_ptr, int* __restrict__ tmp_ptr,
    float* __restrict__ degf, float* __restrict__ ampv, float* __restrict__ attv) {
    __shared__ int s_part[1024];
    __shared__ float s_log[1024];
    int tid = threadIdx.x;
    int base = tid * 3;
    int c0 = 0, c1 = 0, c2 = 0; float lg = 0.f;
    if (base + 0 < NN) { c0 = cnt[base + 0]; lg += logf((float)c0 + 1.f); }
    if (base + 1 < NN) { c1 = cnt[base + 1]; lg += logf((float)c1 + 1.f); }
    if (base + 2 < NN) { c2 = cnt[base + 2]; lg += logf((float)c2 + 1.f); }
    s_part[tid] = c0 + c1 + c2;
    s_log[tid] = lg;
    __syncthreads();
    for (int off = 1; off < 1024; off <<= 1) {
        int v = (tid >= off) ? s_part[tid - off] : 0;
        __syncthreads();
        s_part[tid] += v;
        __syncthreads();
    }
    for (int off = 512; off > 0; off >>= 1) {
        if (tid < off) s_log[tid] += s_log[tid + off];
        __syncthreads();
    }
    float avg = s_log[0] / (float)NN;
    int run = (tid > 0) ? s_part[tid - 1] : 0;
    int cs[3] = {c0, c1, c2};
    for (int i = 0; i < 3; i++) {
        int n = base + i;
        if (n < NN) {
            row_ptr[n] = run; tmp_ptr[n] = run;
            int cc = cs[i];
            float dd = (float)(cc > 0 ? cc : 1);
            degf[n] = dd;
            float ld = logf(dd + 1.f);
            ampv[n] = ld / avg;
            attv[n] = avg / ld;
            run += cc;
        }
    }
    if (tid == 1023) row_ptr[NN] = s_part[1023];
}

__global__ void k_fill(const int* __restrict__ src, const int* __restrict__ dst,
                       const int* __restrict__ attr, int* __restrict__ tmp_ptr,
                       int2* __restrict__ edge_dat) {
    int e = blockIdx.x * blockDim.x + threadIdx.x;
    if (e < NE) {
        int d = dst[e];
        int p = atomicAdd(&tmp_ptr[d], 1);
        edge_dat[p] = make_int2(src[e], attr[e]);
    }
}

// ---------------- embedding ----------------
__global__ void k_embed(const int* __restrict__ x, const float* __restrict__ node_emb,
                        float* __restrict__ h, float* __restrict__ rep) {
    int i = blockIdx.x * blockDim.x + threadIdx.x;
    if (i < NN * D) {
        int n = i / D, d = i - n * D;
        float v = node_emb[x[n] * D + d];
        h[i] = v; rep[i] = v;
    }
}

// ---------------- weight packs ----------------
// f32 Bpack1 (layer-0 path only): Bpack1[f][j] as before
__global__ void k_pack1(const float* __restrict__ W_pre, const float* __restrict__ W_post,
                        int l, float* __restrict__ Bp) {
    int idx = blockIdx.x * blockDim.x + threadIdx.x;
    if (idx >= 300 * NB1) return;
    int f = idx / NB1, j = idx - f * NB1;
    float v;
    if (j < 3600) {
        int s = j / 1800, r = j - s * 1800;
        int t = r / 300, d = r - t * 300;
        v = W_pre[(((size_t)(l * NT + t) * 900) + s * 300 + f) * 300 + d];
    } else {
        int jj = j - 3600;
        int t = jj / FO, o = jj - t * FO;
        v = W_post[((size_t)(l * NT + t) * 3900 + f) * FO + o];
    }
    Bp[idx] = v;
}

// bf16-split B pack for MFMA: layout [kb<KP/8][n<NP][j<8], k = kb*8+j
__global__ void k_pack1b(const float* __restrict__ W_pre, const float* __restrict__ W_post,
                         int l, unsigned short* __restrict__ Bh, unsigned short* __restrict__ Bl) {
    int idx = blockIdx.x * blockDim.x + threadIdx.x;
    if (idx >= (KP / 8) * NP * 8) return;
    int kb = idx / (NP * 8), r = idx - kb * NP * 8;
    int n = r / 8, j = r - n * 8;
    int k = kb * 8 + j;
    float v = 0.f;
    if (k < 300 && n < NB1) {
        if (n < 3600) {
            int s = n / 1800, rr = n - s * 1800;
            int t = rr / 300, d = rr - t * 300;
            v = W_pre[(((size_t)(l * NT + t) * 900) + s * 300 + k) * 300 + d];
        } else {
            int jj = n - 3600;
            int t = jj / FO, o = jj - t * FO;
            v = W_post[((size_t)(l * NT + t) * 3900 + k) * FO + o];
        }
    }
    unsigned short hi = f2bf_rne(v);
    Bh[idx] = hi;
    Bl[idx] = f2bf_rne(v - bf2f(hi));
}

// split h[3000x300] -> Ah/Al [MP x KP] bf16 (zero-padded)
__global__ void k_splitA(const float* __restrict__ A, unsigned short* __restrict__ Ah,
                         unsigned short* __restrict__ Al) {
    int i = blockIdx.x * blockDim.x + threadIdx.x;
    if (i >= MP * KP) return;
    int n = i / KP, k = i - n * KP;
    float v = (n < NN && k < 300) ? A[n * 300 + k] : 0.f;
    unsigned short hi = f2bf_rne(v);
    Ah[i] = hi;
    Al[i] = f2bf_rne(v - bf2f(hi));
}

// Bpost[t][f][c], c<160: c<150 -> W_post[l,t,300 + (c/50)*1200 + f, c%50]; else 0
__global__ void k_packpost(const float* __restrict__ W_post, int l, float* __restrict__ Bp) {
    int idx = blockIdx.x * blockDim.x + threadIdx.x;
    if (idx >= NT * 1200 * 160) return;
    int t = idx / 192000, r = idx - t * 192000;
    int f = r / 160, c = r - f * 160;
    float v = 0.f;
    if (c < 150) {
        int k = c / FO, o = c - k * FO;
        v = W_post[((size_t)(l * NT + t) * 3900 + 300 + k * 1200 + f) * FO + o];
    }
    Bp[idx] = v;
}

// ep4[a][f] = sum_k edge_emb[a,k] * W_edge[l,k,f] + b_edge[l,f]   (4 x 300)
__global__ void k_ep4(const float* __restrict__ edge_emb, const float* __restrict__ W_edge,
                      const float* __restrict__ b_edge, int l, float* __restrict__ ep4) {
    int idx = blockIdx.x * blockDim.x + threadIdx.x;
    if (idx >= 4 * 300) return;
    int a = idx / 300, f = idx - a * 300;
    float s = b_edge[l * 300 + f];
    for (int k = 0; k < 300; k++)
        s = fmaf(edge_emb[a * 300 + k], W_edge[((size_t)l * 300 + k) * 300 + f], s);
    ep4[idx] = s;
}

// Ep[a][t*300+d] = sum_f ep4[a,f] * W_pre[l,t,600+f,d] + b_pre[l,t,d]   (4 x 1800)
__global__ void k_ep_proj(const float* __restrict__ ep4, const float* __restrict__ W_pre,
                          const float* __restrict__ b_pre, int l, float* __restrict__ Ep) {
    int idx = blockIdx.x * blockDim.x + threadIdx.x;
    if (idx >= 4 * 1800) return;
    int a = idx / 1800, c = idx - a * 1800;
    int t = c / 300, d = c - t * 300;
    float s = b_pre[(l * NT + t) * 300 + d];
    for (int f = 0; f < 300; f++)
        s = fmaf(ep4[a * 300 + f], W_pre[(((size_t)(l * NT + t) * 900) + 600 + f) * 300 + d], s);
    Ep[idx] = s;
}

// Wlin_f[f][j] = W_lin[l,f,j]*s_j ; b_f[j] = (b_lin-mean)*s + beta
__global__ void k_pack_lin(const float* __restrict__ W_lin, const float* __restrict__ b_lin,
                           const float* __restrict__ gam, const float* __restrict__ bet,
                           const float* __restrict__ mu, const float* __restrict__ var,
                           int l, float* __restrict__ Wf, float* __restrict__ bf) {
    int idx = blockIdx.x * blockDim.x + threadIdx.x;
    if (idx >= 300 * 300) return;
    int f = idx / 300, j = idx - f * 300;
    float s = gam[l * 300 + j] * rsqrtf(var[l * 300 + j] + EPSV);
    Wf[idx] = W_lin[((size_t)l * 300 + f) * 300 + j] * s;
    if (f == 0) bf[j] = (b_lin[l * 300 + j] - mu[l * 300 + j]) * s + bet[l * 300 + j];
}

// ---------------- generic tiled f32 GEMM ----------------
// EPI 0: plain; EPI 1: +bias, relu, rep += v; EPI 2: +bias, BN, relu (head)
template <int EPI>
__global__ __launch_bounds__(256) void k_gemm(
    const float* __restrict__ A, int lda,
    const float* __restrict__ B, int ldb,
    float* __restrict__ C, int ldc,
    int M, int N, int K,
    const float* __restrict__ bias, float* __restrict__ rep,
    const float* __restrict__ gam, const float* __restrict__ bet,
    const float* __restrict__ mu, const float* __restrict__ var) {
    constexpr int BM = 64, BN = 64, BK = 16, LAS = BM + 4;
    __shared__ float As[BK * LAS];
    __shared__ float Bs[BK * BN];
    int tid = threadIdx.x;
    int tx = tid & 15, ty = tid >> 4;
    int bm = blockIdx.y * BM, bn = blockIdx.x * BN;
    int arow = tid >> 2;
    int akq = (tid & 3) * 4;
    int bj = tid & 63, bk0 = tid >> 6;
    float acc[4][4] = {};
    for (int k0 = 0; k0 < K; k0 += BK) {
        {
            float4 av = make_float4(0.f, 0.f, 0.f, 0.f);
            int grow = bm + arow;
            if (grow < M) {
                int gk = k0 + akq;
                if (gk + 3 < K) {
                    av = *(const float4*)&A[(size_t)grow * lda + gk];
                } else {
                    float t0 = (gk + 0 < K) ? A[(size_t)grow * lda + gk + 0] : 0.f;
                    float t1 = (gk + 1 < K) ? A[(size_t)grow * lda + gk + 1] : 0.f;
                    float t2 = (gk + 2 < K) ? A[(size_t)grow * lda + gk + 2] : 0.f;
                    float t3 = (gk + 3 < K) ? A[(size_t)grow * lda + gk + 3] : 0.f;
                    av = make_float4(t0, t1, t2, t3);
                }
            }
            As[(akq + 0) * LAS + arow] = av.x;
            As[(akq + 1) * LAS + arow] = av.y;
            As[(akq + 2) * LAS + arow] = av.z;
            As[(akq + 3) * LAS + arow] = av.w;
        }
        #pragma unroll
        for (int it = 0; it < 4; ++it) {
            int k = bk0 + it * 4;
            int gk = k0 + k, gj = bn + bj;
            float v = 0.f;
            if (gk < K && gj < N) v = B[(size_t)gk * ldb + gj];
            Bs[k * BN + bj] = v;
        }
        __syncthreads();
        #pragma unroll
        for (int kk = 0; kk < BK; ++kk) {
            float4 a = *(const float4*)&As[kk * LAS + ty * 4];
            float4 b = *(const float4*)&Bs[kk * BN + tx * 4];
            float ar[4] = {a.x, a.y, a.z, a.w};
            float br[4] = {b.x, b.y, b.z, b.w};
            #pragma unroll
            for (int i = 0; i < 4; i++)
                #pragma unroll
                for (int j = 0; j < 4; j++)
                    acc[i][j] = fmaf(ar[i], br[j], acc[i][j]);
        }
        __syncthreads();
    }
    #pragma unroll
    for (int i = 0; i < 4; i++) {
        int r = bm + ty * 4 + i;
        if (r >= M) continue;
        #pragma unroll
        for (int j = 0; j < 4; j++) {
            int c = bn + tx * 4 + j;
            if (c >= N) continue;
            float v = acc[i][j];
            if (EPI == 1) {
                v += bias[c];
                v = fmaxf(v, 0.f);
                C[(size_t)r * ldc + c] = v;
                rep[(size_t)r * ldc + c] += v;
            } else if (EPI == 2) {
                v += bias[c];
                v = (v - mu[c]) * rsqrtf(var[c] + EPSV) * gam[c] + bet[c];
                v = fmaxf(v, 0.f);
                C[(size_t)r * ldc + c] = v;
            } else {
                C[(size_t)r * ldc + c] = v;
            }
        }
    }
}

// ---------------- MFMA GEMM1: C[3000xNB1] = A[3000x300] @ B[300xNB1] ------
// bf16 3-product split (AhBh + AhBl + AlBh) on mfma_f32_16x16x32_bf16.
// Block: 256 thr = 4 waves (2x2), wave tile 32x32 (2x2 fragments of 16x16).
// A layout: lane holds A[row0+i*16+(lane&15)][ks*32+(lane>>4)*8 + 0..7]
// B layout: lane holds B[k][col0+j*16+(lane&15)] via pack [kb][n][8]
// C layout (m89-verified): col=lane&15, row=(lane>>4)*4+reg
__global__ __launch_bounds__(256) void k_gemm1m(
    const unsigned short* __restrict__ Ah, const unsigned short* __restrict__ Al,
    const unsigned short* __restrict__ Bh, const unsigned short* __restrict__ Bl,
    float* __restrict__ C) {
    int tid = threadIdx.x;
    int wave = tid >> 6, lane = tid & 63;
    int wr = wave >> 1, wc = wave & 1;
    int lr = lane & 15, lg = lane >> 4;
    int row0 = blockIdx.y * 64 + wr * 32;
    int col0 = blockIdx.x * 64 + wc * 32;
    floatx4 acc00 = {0.f, 0.f, 0.f, 0.f}, acc01 = {0.f, 0.f, 0.f, 0.f};
    floatx4 acc10 = {0.f, 0.f, 0.f, 0.f}, acc11 = {0.f, 0.f, 0.f, 0.f};
    const unsigned short* paH = Ah + (size_t)(row0 + lr) * KP + lg * 8;
    const unsigned short* paL = Al + (size_t)(row0 + lr) * KP + lg * 8;
    const unsigned short* pbH = Bh + ((size_t)lg * NP + col0 + lr) * 8;
    const unsigned short* pbL = Bl + ((size_t)lg * NP + col0 + lr) * 8;
    #pragma unroll
    for (int ks = 0; ks < KP / 32; ++ks) {
        int ao = ks * 32;
        size_t bo = (size_t)ks * 4 * NP * 8;
        short8 ah0 = *(const short8*)(paH + ao);
        short8 ah1 = *(const short8*)(paH + 16 * KP + ao);
        short8 al0 = *(const short8*)(paL + ao);
        short8 al1 = *(const short8*)(paL + 16 * KP + ao);
        short8 bh0 = *(const short8*)(pbH + bo);
        short8 bh1 = *(const short8*)(pbH + bo + 128);
        short8 bl0 = *(const short8*)(pbL + bo);
        short8 bl1 = *(const short8*)(pbL + bo + 128);
        acc00 = __builtin_amdgcn_mfma_f32_16x16x32_bf16(ah0, bh0, acc00, 0, 0, 0);
        acc01 = __builtin_amdgcn_mfma_f32_16x16x32_bf16(ah0, bh1, acc01, 0, 0, 0);
        acc10 = __builtin_amdgcn_mfma_f32_16x16x32_bf16(ah1, bh0, acc10, 0, 0, 0);
        acc11 = __builtin_amdgcn_mfma_f32_16x16x32_bf16(ah1, bh1, acc11, 0, 0, 0);
        acc00 = __builtin_amdgcn_mfma_f32_16x16x32_bf16(ah0, bl0, acc00, 0, 0, 0);
        acc01 = __builtin_amdgcn_mfma_f32_16x16x32_bf16(ah0, bl1, acc01, 0, 0, 0);
        acc10 = __builtin_amdgcn_mfma_f32_16x16x32_bf16(ah1, bl0, acc10, 0, 0, 0);
        acc11 = __builtin_amdgcn_mfma_f32_16x16x32_bf16(ah1, bl1, acc11, 0, 0, 0);
        acc00 = __builtin_amdgcn_mfma_f32_16x16x32_bf16(al0, bh0, acc00, 0, 0, 0);
        acc01 = __builtin_amdgcn_mfma_f32_16x16x32_bf16(al0, bh1, acc01, 0, 0, 0);
        acc10 = __builtin_amdgcn_mfma_f32_16x16x32_bf16(al1, bh0, acc10, 0, 0, 0);
        acc11 = __builtin_amdgcn_mfma_f32_16x16x32_bf16(al1, bh1, acc11, 0, 0, 0);
    }
    #pragma unroll
    for (int i = 0; i < 2; i++) {
        #pragma unroll
        for (int j = 0; j < 2; j++) {
            floatx4 a = (i == 0) ? ((j == 0) ? acc00 : acc01)
                                 : ((j == 0) ? acc10 : acc11);
            int col = col0 + j * 16 + lr;
            #pragma unroll
            for (int r = 0; r < 4; r++) {
                int row = row0 + i * 16 + lg * 4 + r;
                if (row < NN && col < NB1)
                    C[(size_t)row * NB1 + col] = a[r];
            }
        }
    }
}

// ---------------- post GEMM: split-K=5 per tower, towers in z ----------------
__global__ __launch_bounds__(256) void k_gemmp(const float* __restrict__ agg,
                                               const float* __restrict__ Bp,
                                               float* __restrict__ P) {
    constexpr int BM = 64, BN = 160, BK = 16, LAS = BM + 4, KC = 240;
    __shared__ float As[BK * LAS];
    __shared__ float Bs[BK * BN];
    int z = blockIdx.z;
    int t = z % 6, kc = z / 6;
    const float* A = agg + t * 1200 + kc * KC;        // row stride 7200
    const float* B = Bp + t * 192000 + kc * KC * 160; // row stride 160
    float* C = P + (size_t)z * 480000;
    int tid = threadIdx.x;
    int tx = tid & 15, ty = tid >> 4;
    int bm = blockIdx.y * BM;
    float acc[4][10] = {};
    for (int k0 = 0; k0 < KC; k0 += BK) {
        {
            int row = tid >> 2, kq = (tid & 3) * 4;
            int grow = bm + row;
            float4 av = make_float4(0.f, 0.f, 0.f, 0.f);
            if (grow < 3000) av = *(const float4*)&A[(size_t)grow * 7200 + k0 + kq];
            As[(kq + 0) * LAS + row] = av.x;
            As[(kq + 1) * LAS + row] = av.y;
            As[(kq + 2) * LAS + row] = av.z;
            As[(kq + 3) * LAS + row] = av.w;
        }
        #pragma unroll
        for (int it = 0; it < 3; ++it) {
            int i = tid + it * 256;
            if (i < 640) {
                int k = i / 40, c = (i - k * 40) * 4;
                *(float4*)&Bs[k * BN + c] = *(const float4*)&B[(size_t)(k0 + k) * 160 + c];
            }
        }
        __syncthreads();
        #pragma unroll
        for (int kk = 0; kk < BK; ++kk) {
            float a[4], b[10];
            *(float4*)&a[0] = *(const float4*)&As[kk * LAS + ty * 4];
            #pragma unroll
            for (int j = 0; j < 10; j++) b[j] = Bs[kk * BN + tx * 10 + j];
            #pragma unroll
            for (int i = 0; i < 4; i++)
                #pragma unroll
                for (int j = 0; j < 10; j++)
                    acc[i][j] = fmaf(a[i], b[j], acc[i][j]);
        }
        __syncthreads();
    }
    int r0 = bm + ty * 4, c0 = tx * 10;
    #pragma unroll
    for (int i = 0; i < 4; i++) {
        int r = r0 + i;
        if (r >= 3000) break;
        #pragma unroll
        for (int j = 0; j < 10; j++)
            C[(size_t)r * 160 + c0 + j] = acc[i][j];
    }
}

// ---------------- aggregation (float4) ----------------
__global__ __launch_bounds__(256) void k_agg(
    const float* __restrict__ HH, const float* __restrict__ Ep,
    const int* __restrict__ row_ptr, const int2* __restrict__ edge_dat,
    const float* __restrict__ degf, const int* __restrict__ xv, int use_vocab,
    float* __restrict__ agg) {
    int n = blockIdx.x;
    int e0 = row_ptr[n], e1 = row_ptr[n + 1];
    int cnt = e1 - e0;
    float cntf = (float)cnt;
    float deg = degf[n];
    float inv_deg = 1.f / deg;
    int nrow = use_vocab ? xv[n] : n;
    const float* hdrow = HH + (size_t)nrow * NB1;
    for (int c4 = threadIdx.x; c4 < 450; c4 += 256) {
        int c = c4 * 4;
        float sx = 0.f, sy = 0.f, sz = 0.f, sw = 0.f;
        float qx = 0.f, qy = 0.f, qz = 0.f, qw = 0.f;
        float mnx = INFINITY, mny = INFINITY, mnz = INFINITY, mnw = INFINITY;
        float mxx = -INFINITY, mxy = -INFINITY, mxz = -INFINITY, mxw = -INFINITY;
        for (int e = e0; e < e1; ++e) {
            int2 sa = edge_dat[e];
            int srow = use_vocab ? xv[sa.x] : sa.x;
            float4 hv = *(const float4*)&HH[(size_t)srow * NB1 + 1800 + c];
            float4 ev = *(const float4*)&Ep[(size_t)sa.y * 1800 + c];
            float vx = hv.x + ev.x, vy = hv.y + ev.y, vz = hv.z + ev.z, vw = hv.w + ev.w;
            sx += vx; sy += vy; sz += vz; sw += vw;
            qx = fmaf(vx, vx, qx); qy = fmaf(vy, vy, qy);
            qz = fmaf(vz, vz, qz); qw = fmaf(vw, vw, qw);
            mnx = fminf(mnx, vx); mny = fminf(mny, vy);
            mnz = fminf(mnz, vz); mnw = fminf(mnw, vw);
            mxx = fmaxf(mxx, vx); mxy = fmaxf(mxy, vy);
            mxz = fmaxf(mxz, vz); mxw = fmaxf(mxw, vw);
        }
        float4 hd = *(const float4*)&hdrow[c];
        float4 mean, mnv, mxv, stdv;
        {
            mean.x = (cntf * hd.x + sx) * inv_deg;
            mean.y = (cntf * hd.y + sy) * inv_deg;
            mean.z = (cntf * hd.z + sz) * inv_deg;
            mean.w = (cntf * hd.w + sw) * inv_deg;
            if (cnt > 0) {
                mnv.x = hd.x + mnx; mnv.y = hd.y + mny; mnv.z = hd.z + mnz; mnv.w = hd.w + mnw;
                mxv.x = hd.x + mxx; mxv.y = hd.y + mxy; mxv.z = hd.z + mxz; mxv.w = hd.w + mxw;
            } else {
                mnv = make_float4(0.f, 0.f, 0.f, 0.f);
                mxv = make_float4(0.f, 0.f, 0.f, 0.f);
            }
            float vrx = (cntf * hd.x * hd.x + 2.f * hd.x * sx + qx) * inv_deg - mean.x * mean.x;
            float vry = (cntf * hd.y * hd.y + 2.f * hd.y * sy + qy) * inv_deg - mean.y * mean.y;
            float vrz = (cntf * hd.z * hd.z + 2.f * hd.z * sz + qz) * inv_deg - mean.z * mean.z;
            float vrw = (cntf * hd.w * hd.w + 2.f * hd.w * sw + qw) * inv_deg - mean.w * mean.w;
            stdv.x = sqrtf(fmaxf(vrx, 0.f) + EPSV);
            stdv.y = sqrtf(fmaxf(vry, 0.f) + EPSV);
            stdv.z = sqrtf(fmaxf(vrz, 0.f) + EPSV);
            stdv.w = sqrtf(fmaxf(vrw, 0.f) + EPSV);
        }
        int t = c / 300, d = c - t * 300;
        float* arow = agg + (size_t)n * 7200 + (size_t)t * 1200 + d;
        *(float4*)&arow[0]   = mean;
        *(float4*)&arow[300] = mnv;
        *(float4*)&arow[600] = mxv;
        *(float4*)&arow[900] = stdv;
    }
}

// out_pre[n][t*50+o] = Xp(from HsHd col 3600+) + sum_kc(P1 + amp*P2 + att*P3) + b_post
__global__ void k_combine(const float* __restrict__ HH, const float* __restrict__ P,
                          const float* __restrict__ ampv, const float* __restrict__ attv,
                          const float* __restrict__ b_post_l, const int* __restrict__ xv,
                          int use_vocab, float* __restrict__ out_pre) {
    int i = blockIdx.x * blockDim.x + threadIdx.x;
    if (i >= NN * D) return;
    int n = i / D, j = i - n * D;
    int t = j / FO, o = j - t * FO;
    int nrow = use_vocab ? xv[n] : n;
    float p1 = 0.f, p2 = 0.f, p3 = 0.f;
    #pragma unroll
    for (int kc = 0; kc < 5; kc++) {
        const float* Pr = P + ((size_t)(kc * 6 + t) * 3000 + n) * 160;
        p1 += Pr[o];
        p2 += Pr[50 + o];
        p3 += Pr[100 + o];
    }
    float v = HH[(size_t)nrow * NB1 + 3600 + j] + p1 + ampv[n] * p2 + attv[n] * p3
              + b_post_l[t * FO + o];
    out_pre[i] = v;
}

// ---------------- pooling + head ----------------
__global__ __launch_bounds__(256) void k_pool(const float* __restrict__ rep,
                                              const int* __restrict__ batch,
                                              float* __restrict__ g) {
    __shared__ int s_lo, s_hi;
    int b = blockIdx.x;
    if (threadIdx.x == 0) {
        int lo = 0, hi = NN;
        while (lo < hi) { int m = (lo + hi) >> 1; if (batch[m] < b) lo = m + 1; else hi = m; }
        s_lo = lo;
        int lo2 = lo, hi2 = NN;
        while (lo2 < hi2) { int m = (lo2 + hi2) >> 1; if (batch[m] < b + 1) lo2 = m + 1; else hi2 = m; }
        s_hi = lo2;
    }
    __syncthreads();
    int lo = s_lo, hi = s_hi;
    for (int j = threadIdx.x; j < D; j += blockDim.x) {
        float s = 0.f;
        for (int n = lo; n < hi; ++n) s += rep[(size_t)n * D + j];
        g[b * D + j] = s;
    }
}

__global__ void k_head2(const float* __restrict__ g2, const float* __restrict__ w2,
                        const float* __restrict__ b2, float* __restrict__ out) {
    int b = blockIdx.x;
    int tid = threadIdx.x;  // 64 threads
    float s = 0.f;
    for (int k = tid; k < 300; k += 64) s += g2[b * 300 + k] * w2[k];
    for (int off = 32; off; off >>= 1) s += __shfl_down(s, off, 64);
    if (tid == 0) out[b] = s + b2[0];
}

// ---------------- launch ----------------
extern "C" void kernel_launch(void* const* d_in, const int* in_sizes, int n_in,
                              void* d_out, int out_size, void* d_ws, size_t ws_size,
                              hipStream_t stream) {
    const int* x      = (const int*)d_in[0];
    const int* ei     = (const int*)d_in[1];
    const int* src    = ei;
    const int* dst    = ei + NE;
    const int* eattr  = (const int*)d_in[2];
    const int* batch  = (const int*)d_in[3];
    const float* node_emb = (const float*)d_in[5];
    const float* edge_emb = (const float*)d_in[6];
    const float* W_edge   = (const float*)d_in[7];
    const float* b_edge   = (const float*)d_in[8];
    const float* W_pre    = (const float*)d_in[9];
    const float* b_pre    = (const float*)d_in[10];
    const float* W_post   = (const float*)d_in[11];
    const float* b_post   = (const float*)d_in[12];
    const float* W_lin    = (const float*)d_in[13];
    const float* b_lin    = (const float*)d_in[14];
    const float* bn_gamma = (const float*)d_in[15];
    const float* bn_beta  = (const float*)d_in[16];
    const float* bn_mean  = (const float*)d_in[17];
    const float* bn_var   = (const float*)d_in[18];
    const float* head_w0  = (const float*)d_in[19];
    const float* head_b0  = (const float*)d_in[20];
    const float* gn0_g    = (const float*)d_in[21];
    const float* gn0_b    = (const float*)d_in[22];
    const float* gn0_m    = (const float*)d_in[23];
    const float* gn0_v    = (const float*)d_in[24];
    const float* head_w1  = (const float*)d_in[25];
    const float* head_b1  = (const float*)d_in[26];
    const float* gn1_g    = (const float*)d_in[27];
    const float* gn1_b    = (const float*)d_in[28];
    const float* gn1_m    = (const float*)d_in[29];
    const float* gn1_v    = (const float*)d_in[30];
    const float* head_w2  = (const float*)d_in[31];
    const float* head_b2  = (const float*)d_in[32];
    float* out = (float*)d_out;

    unsigned char* base = (unsigned char*)d_ws;
    size_t off = 0;
    auto alloc = [&](size_t bytes) -> void* {
        void* p = base + off;
        off += (bytes + 255) & ~(size_t)255;
        return p;
    };
    int*   cnt      = (int*)alloc(NN * 4);
    int*   row_ptr  = (int*)alloc((NN + 1) * 4);
    int*   tmp_ptr  = (int*)alloc(NN * 4);
    int2*  edge_dat = (int2*)alloc(NE * 8);
    float* degf     = (float*)alloc(NN * 4);
    float* ampv     = (float*)alloc(NN * 4);
    float* attv     = (float*)alloc(NN * 4);
    float* h        = (float*)alloc((size_t)NN * D * 4);
    float* rep      = (float*)alloc((size_t)NN * D * 4);
    float* HsHd     = (float*)alloc((size_t)NN * NB1 * 4);
    float* Bpack1   = (float*)alloc((size_t)300 * NB1 * 4);
    unsigned short* Ah = (unsigned short*)alloc((size_t)MP * KP * 2);
    unsigned short* Al = (unsigned short*)alloc((size_t)MP * KP * 2);
    unsigned short* Bh = (unsigned short*)alloc((size_t)(KP / 8) * NP * 8 * 2);
    unsigned short* Bl = (unsigned short*)alloc((size_t)(KP / 8) * NP * 8 * 2);
    float* ep4      = (float*)alloc(4 * 300 * 4);
    float* Ep       = (float*)alloc(4 * 1800 * 4);
    float* agg      = (float*)alloc((size_t)NN * 7200 * 4);
    float* Bpost    = (float*)alloc((size_t)NT * 1200 * 160 * 4);
    float* P        = (float*)alloc((size_t)30 * 3000 * 160 * 4);
    float* out_pre  = (float*)alloc((size_t)NN * D * 4);
    float* Wlin_f   = (float*)alloc((size_t)300 * 300 * 4);
    float* b_f      = (float*)alloc(300 * 4);
    float* gsum     = (float*)alloc(NG * D * 4);
    float* gbuf0    = (float*)alloc(NG * 600 * 4);
    float* gbuf1    = (float*)alloc(NG * 300 * 4);
    (void)ws_size; (void)n_in; (void)in_sizes; (void)out_size;

    hipMemsetAsync(cnt, 0, NN * 4, stream);
    k_hist<<<(NE + 255) / 256, 256, 0, stream>>>(dst, cnt);
    k_scan<<<1, 1024, 0, stream>>>(cnt, row_ptr, tmp_ptr, degf, ampv, attv);
    k_fill<<<(NE + 255) / 256, 256, 0, stream>>>(src, dst, eattr, tmp_ptr, edge_dat);
    k_embed<<<(NN * D + 255) / 256, 256, 0, stream>>>(x, node_emb, h, rep);

    for (int l = 0; l < 3; ++l) {  // layer 3 (l==3) output is unused by the reference
        const float* Ain = (l == 0) ? node_emb : h;
        int M = (l == 0) ? 16 : NN;
        int uv = (l == 0) ? 1 : 0;

        if (l == 0) {
            k_pack1<<<(300 * NB1 + 255) / 256, 256, 0, stream>>>(W_pre, W_post, l, Bpack1);
            k_gemm<0><<<dim3((NB1 + 63) / 64, 1, 1), 256, 0, stream>>>(
                Ain, 300, Bpack1, NB1, HsHd, NB1, M, NB1, 300,
                nullptr, nullptr, nullptr, nullptr, nullptr, nullptr);
        } else {
            k_splitA<<<(MP * KP + 255) / 256, 256, 0, stream>>>(h, Ah, Al);
            k_pack1b<<<((KP / 8) * NP * 8 + 255) / 256, 256, 0, stream>>>(
                W_pre, W_post, l, Bh, Bl);
            k_gemm1m<<<dim3(NP / 64, MP / 64, 1), 256, 0, stream>>>(Ah, Al, Bh, Bl, HsHd);
        }

        k_ep4<<<(1200 + 255) / 256, 256, 0, stream>>>(edge_emb, W_edge, b_edge, l, ep4);
        k_ep_proj<<<(7200 + 255) / 256, 256, 0, stream>>>(ep4, W_pre, b_pre, l, Ep);

        k_agg<<<NN, 256, 0, stream>>>(HsHd, Ep, row_ptr, edge_dat, degf, x, uv, agg);

        k_packpost<<<(NT * 1200 * 160 + 255) / 256, 256, 0, stream>>>(W_post, l, Bpost);
        k_gemmp<<<dim3(1, 47, 30), 256, 0, stream>>>(agg, Bpost, P);

        k_combine<<<(NN * D + 255) / 256, 256, 0, stream>>>(
            HsHd, P, ampv, attv, b_post + l * NT * FO, x, uv, out_pre);

        k_pack_lin<<<(300 * 300 + 255) / 256, 256, 0, stream>>>(
            W_lin, b_lin, bn_gamma, bn_beta, bn_mean, bn_var, l, Wlin_f, b_f);
        k_gemm<1><<<dim3(5, 47, 1), 256, 0, stream>>>(
            out_pre, 300, Wlin_f, 300, h, 300, NN, 300, 300,
            b_f, rep, nullptr, nullptr, nullptr, nullptr);
    }

    k_pool<<<NG, 256, 0, stream>>>(rep, batch, gsum);
    k_gemm<2><<<dim3(10, 1, 1), 256, 0, stream>>>(
        gsum, 300, head_w0, 600, gbuf0, 600, NG, 600, 300,
        head_b0, nullptr, gn0_g, gn0_b, gn0_m, gn0_v);
    k_gemm<2><<<dim3(5, 1, 1), 256, 0, stream>>>(
        gbuf0, 600, head_w1, 300, gbuf1, 300, NG, 300, 600,
        head_b1, nullptr, gn1_g, gn1_b, gn1_m, gn1_v);
    k_head2<<<NG, 64, 0, stream>>>(gbuf1, head_w2, head_b2, out);
}